// Round 1
// 528.065 us; speedup vs baseline: 1.1471x; 1.1471x over previous
//
#include <hip/hip_runtime.h>
#include <hip/hip_bf16.h>

#define B_   2
#define C_   64
#define H_   48
#define W_   48
#define N_   (H_*W_)     // 2304
#define NH_  8
#define HD_  8
#define EPS_ 1e-5f
#define S2_  0.125f      // scale^2 = 1/hd
#define LOG2E_ 1.44269504f
#define FS_  (S2_ * LOG2E_)
#define S_   ((size_t)B_ * C_ * N_)   // 294912 floats per workspace slot
#define CN_  ((size_t)C_ * N_)        // 147456 floats per image

typedef unsigned short u16;
typedef __attribute__((ext_vector_type(8))) short short8v;
typedef __attribute__((ext_vector_type(4))) float f32x4;
union F8 { uint4 u4; short8v s; unsigned int w[4]; };

__device__ __forceinline__ float wsum64(float v) {
#pragma unroll
  for (int o = 32; o > 0; o >>= 1) v += __shfl_xor(v, o, 64);
  return v;
}

__device__ __forceinline__ float ln_val(float t, float g, float b) {
  float mu  = wsum64(t) * (1.0f / 64.0f);
  float d   = t - mu;
  float var = wsum64(d * d) * (1.0f / 64.0f);
  return d * rsqrtf(var + EPS_) * g + b;
}

// round-to-nearest-even f32 -> bf16 (finite inputs only)
__device__ __forceinline__ u16 f2bf(float x) {
  union { float f; unsigned int u; } a; a.f = x;
  unsigned int r = a.u + 0x7fffu + ((a.u >> 16) & 1u);
  return (u16)(r >> 16);
}

// ---- fused 1x1 pconv + BN + 3x LayerNorm; block = one (b,n) row ----------
__global__ __launch_bounds__(64) void k_pre(
    const float* __restrict__ x, const float* __restrict__ y,
    const float* __restrict__ pw, const float* __restrict__ pb,
    const float* g, const float* bb, const float* m, const float* v,
    const float* lnxg, const float* lnxb,
    const float* lnyg, const float* lnyb,
    const float* lnzg, const float* lnzb,
    float* __restrict__ xl, float* __restrict__ yl, float* __restrict__ zl) {
  __shared__ float xs[64], ys[64];
  int row = blockIdx.x;            // b*N + n
  int c = threadIdx.x;
  int b = row / N_, n = row % N_;
  float xv = x[(size_t)(b * C_ + c) * N_ + n];
  float yv = y[(size_t)(b * C_ + c) * N_ + n];
  xs[c] = xv; ys[c] = yv;
  __syncthreads();
  const float4* wr  = (const float4*)(pw + (size_t)c * 2 * C_);
  const float4* xs4 = (const float4*)xs;
  const float4* ys4 = (const float4*)ys;
  float acc = pb[c];
#pragma unroll
  for (int t = 0; t < 16; ++t) {
    float4 a = xs4[t], wv = wr[t];
    acc += a.x * wv.x + a.y * wv.y + a.z * wv.z + a.w * wv.w;
  }
#pragma unroll
  for (int t = 0; t < 16; ++t) {
    float4 a = ys4[t], wv = wr[16 + t];
    acc += a.x * wv.x + a.y * wv.y + a.z * wv.z + a.w * wv.w;
  }
  float s  = g[c] * rsqrtf(v[c] + EPS_);
  float sh = bb[c] - m[c] * s;
  float tx = xv * s + sh;
  xl[(size_t)row * C_ + c] = ln_val(tx, lnxg[c], lnxb[c]);
  float ty = yv * s + sh;
  yl[(size_t)row * C_ + c] = ln_val(ty, lnyg[c], lnyb[c]);
  float tz = acc * s + sh;
  zl[(size_t)row * C_ + c] = ln_val(tz, lnzg[c], lnzb[c]);
}

// ------------- fused qv (both branches) + k projection --------------------
// NEW: emits bf16 for the MFMA attention:
//   qxb [bh][n][8]  (scale FS_ folded in), qyb [bh][n][8]
//   kbf [bh][n][8]
//   vt  [bh][16][N]  rows 0-7 = Vx dims, rows 8-15 = Vy dims (transposed)
__global__ void k_qvk(const float* __restrict__ lnb, const float* __restrict__ zl,
                      const float* __restrict__ qvw, const float* __restrict__ qvb,
                      const float* __restrict__ kw, const float* __restrict__ kb,
                      u16* __restrict__ qxb, u16* __restrict__ qyb,
                      u16* __restrict__ kbf, u16* __restrict__ vt) {
  int z = blockIdx.z;
  if (z < 2) {
    int idx = blockIdx.x * 256 + threadIdx.x;   // B*N*128
    int j = idx & 127;
    int row = idx >> 7;
    int b = row / N_, n = row % N_;
    const float4* ir = (const float4*)(lnb + z * S_ + (size_t)row * C_);
    const float4* wr = (const float4*)(qvw + (size_t)j * C_);
    float acc = qvb[j];
#pragma unroll
    for (int t = 0; t < 16; ++t) {
      float4 a = ir[t], wv = wr[t];
      acc += a.x * wv.x + a.y * wv.y + a.z * wv.z + a.w * wv.w;
    }
    int jj = j & 63;
    int h = jj >> 3, d = jj & 7;
    int bh = b * NH_ + h;
    if (j < C_) {   // q
      float val = (z == 0) ? acc * FS_ : acc;
      u16* dst = (z == 0) ? qxb : qyb;
      dst[((size_t)bh * N_ + n) * 8 + d] = f2bf(val);
    } else {        // v (transposed store)
      vt[((size_t)bh * 16 + z * 8 + d) * N_ + n] = f2bf(acc);
    }
  } else {
    if (blockIdx.x >= 1152) return;
    int idx = blockIdx.x * 256 + threadIdx.x;   // B*N*64
    int j = idx & 63;
    int row = idx >> 6;
    int b = row / N_, n = row % N_;
    const float4* ir = (const float4*)(zl + (size_t)row * C_);
    const float4* wr = (const float4*)(kw + (size_t)j * C_);
    float acc = kb[j];
#pragma unroll
    for (int t = 0; t < 16; ++t) {
      float4 a = ir[t], wv = wr[t];
      acc += a.x * wv.x + a.y * wv.y + a.z * wv.z + a.w * wv.w;
    }
    int h = j >> 3, d = j & 7;
    kbf[((size_t)(b * NH_ + h) * N_ + n) * 8 + d] = f2bf(acc);
  }
}

// ---------------- attention v8: MFMA flash, 16-q tile, dual-branch --------
// grid (N/16, 16bh), block 128 (2 waves, each wave = half the keys).
// Swapped QK^T (S^T = K*Q^T) so C cols = q; P rebuilt into A-frag layout by
// 8 ds_bpermute per 32-key chunk; one PV MFMA covers Vx|Vy (cols 0-7|8-15).
__global__ __launch_bounds__(128, 5) void k_attn8(
    const u16* __restrict__ qx, const u16* __restrict__ qy,
    const u16* __restrict__ kk, const u16* __restrict__ vt,
    float* __restrict__ outx, float* __restrict__ outy) {
  __shared__ float sAcc[2][4][64];
  __shared__ float sL[2][16];
  int qt = blockIdx.x, bh = blockIdx.y;
  int tid = threadIdx.x;
  int lane = tid & 63;
  int wave = tid >> 6;
  int l15 = lane & 15;
  int q0 = qt * 16;

  // Q fragments: lanes 0-15 hold the 16x8 tile (k=0..7), lanes >=16 ZERO
  // (zero B-side kills the padded k>=8 slots regardless of A garbage).
  F8 qxf, qyf;
  size_t qoff = ((size_t)bh * N_ + q0 + l15) * 8;
  qxf.u4 = *(const uint4*)(qx + qoff);
  qyf.u4 = *(const uint4*)(qy + qoff);
  if (lane >= 16) {
    qxf.u4 = make_uint4(0u, 0u, 0u, 0u);
    qyf.u4 = make_uint4(0u, 0u, 0u, 0u);
  }

  int key0 = wave * (N_ / 2);
  const uint4* kp = (const uint4*)(kk + (size_t)bh * N_ * 8) + key0 + l15;
  const uint4* vp = (const uint4*)(vt + ((size_t)bh * 16 + l15) * N_ + key0)
                    + (lane >> 4);
  // bpermute source lanes for P A-frag build (dest lane (g,q) pulls keys
  // 8g..8g+7: lanes 32*(g&1)+q and +16, subtile sel = g>>1)
  int addr0 = (((lane >> 4) & 1) * 32 + l15) * 4;
  int addr1 = addr0 + 64;
  int thi = lane >> 5;

  f32x4 acc = {0.f, 0.f, 0.f, 0.f};
  const f32x4 z4 = {0.f, 0.f, 0.f, 0.f};
  float lsum = 0.f;

  F8 ka, kb2, vf;
  ka.u4 = kp[0]; kb2.u4 = kp[16]; vf.u4 = *vp;
  for (int c = 0; c < 36; ++c) {
    F8 kaC = ka, kbC = kb2, vfC = vf;
    kp += 32; vp += 4;
    ka.u4 = kp[0]; kb2.u4 = kp[16]; vf.u4 = *vp;   // prefetch next chunk

    // S^T tiles: rows=keys, cols=q. C layout: col=l&15, row=4*(l>>4)+reg.
    f32x4 s1a = __builtin_amdgcn_mfma_f32_16x16x32_bf16(kaC.s, qxf.s, z4, 0, 0, 0);
    f32x4 s2a = __builtin_amdgcn_mfma_f32_16x16x32_bf16(kaC.s, qyf.s, z4, 0, 0, 0);
    f32x4 s1b = __builtin_amdgcn_mfma_f32_16x16x32_bf16(kbC.s, qxf.s, z4, 0, 0, 0);
    f32x4 s2b = __builtin_amdgcn_mfma_f32_16x16x32_bf16(kbC.s, qyf.s, z4, 0, 0, 0);

    float p00 = exp2f(s1a[0] * s2a[0]), p01 = exp2f(s1a[1] * s2a[1]);
    float p02 = exp2f(s1a[2] * s2a[2]), p03 = exp2f(s1a[3] * s2a[3]);
    float p10 = exp2f(s1b[0] * s2b[0]), p11 = exp2f(s1b[1] * s2b[1]);
    float p12 = exp2f(s1b[2] * s2b[2]), p13 = exp2f(s1b[3] * s2b[3]);
    lsum += ((p00 + p01) + (p02 + p03)) + ((p10 + p11) + (p12 + p13));

    unsigned int pk00, pk10, pk01, pk11;
    asm("v_cvt_pk_bf16_f32 %0, %1, %2" : "=v"(pk00) : "v"(p00), "v"(p01));
    asm("v_cvt_pk_bf16_f32 %0, %1, %2" : "=v"(pk10) : "v"(p02), "v"(p03));
    asm("v_cvt_pk_bf16_f32 %0, %1, %2" : "=v"(pk01) : "v"(p10), "v"(p11));
    asm("v_cvt_pk_bf16_f32 %0, %1, %2" : "=v"(pk11) : "v"(p12), "v"(p13));

    int b00 = __builtin_amdgcn_ds_bpermute(addr0, (int)pk00);
    int b01 = __builtin_amdgcn_ds_bpermute(addr0, (int)pk01);
    int b10 = __builtin_amdgcn_ds_bpermute(addr0, (int)pk10);
    int b11 = __builtin_amdgcn_ds_bpermute(addr0, (int)pk11);
    int c00 = __builtin_amdgcn_ds_bpermute(addr1, (int)pk00);
    int c01 = __builtin_amdgcn_ds_bpermute(addr1, (int)pk01);
    int c10 = __builtin_amdgcn_ds_bpermute(addr1, (int)pk10);
    int c11 = __builtin_amdgcn_ds_bpermute(addr1, (int)pk11);

    F8 pf;   // A-frag: row=q=l&15, keys 8g+0..7 as 4 packed bf16 pairs
    pf.w[0] = (unsigned int)(thi ? b01 : b00);
    pf.w[1] = (unsigned int)(thi ? b11 : b10);
    pf.w[2] = (unsigned int)(thi ? c01 : c00);
    pf.w[3] = (unsigned int)(thi ? c11 : c10);
    acc = __builtin_amdgcn_mfma_f32_16x16x32_bf16(pf.s, vfC.s, acc, 0, 0, 0);
  }

  // row-sum L per q (cols fixed per lane; sum over the 4 lane groups)
  lsum += __shfl_xor(lsum, 16, 64);
  lsum += __shfl_xor(lsum, 32, 64);
  if (lane < 16) sL[wave][lane] = lsum;
#pragma unroll
  for (int r = 0; r < 4; ++r) sAcc[wave][r][lane] = acc[r];
  __syncthreads();
  if (wave == 0) {
    float Linv = 1.f / (sL[0][l15] + sL[1][l15]);   // L for q = l15
    int b = bh >> 3, h = bh & 7;
    int d = l15 & 7;
    float* ob = (l15 < 8) ? outx : outy;
    size_t cbase = (size_t)b * N_ * C_ + (size_t)h * 8 + d;
#pragma unroll
    for (int r = 0; r < 4; ++r) {
      int qrow = 4 * (lane >> 4) + r;              // PV C row = q
      float li = __shfl(Linv, qrow, 64);
      float a = sAcc[0][r][lane] + sAcc[1][r][lane];
      ob[cbase + (size_t)(q0 + qrow) * C_] = a * li;
    }
  }
}

// -------- proj v2: 2 couts + 2 px per thread (att rows shared) ------------
// grid (18, C_/2, 2*B_), block 64. out layout z*CN, z = branch*B_ + b.
__global__ __launch_bounds__(64) void k_proj2(
    const float* __restrict__ attbase,
    const float* __restrict__ x, const float* __restrict__ y,
    const float* bg, const float* bb2, const float* bm, const float* bv,
    const float* __restrict__ pw, const float* __restrict__ pbias,
    float* __restrict__ outbase) {
  int p = blockIdx.x * 128 + threadIdx.x * 2;
  int c0 = blockIdx.y * 2;
  int z = blockIdx.z;
  int branch = z >> 1, b = z & 1;
  const float* att = attbase + branch * S_ + (size_t)b * N_ * C_;
  const float4* w0 = (const float4*)(pw + (size_t)c0 * C_);
  const float4* w1 = (const float4*)(pw + (size_t)(c0 + 1) * C_);
  const float4* ar0 = (const float4*)(att + (size_t)p * C_);
  const float4* ar1 = (const float4*)(att + (size_t)(p + 1) * C_);
  float bias0 = pbias[c0], bias1 = pbias[c0 + 1];
  float a00 = bias0, a01 = bias0, a10 = bias1, a11 = bias1;
#pragma unroll
  for (int t = 0; t < 16; ++t) {
    float4 v0 = ar0[t], v1 = ar1[t];
    float4 u = w0[t], w = w1[t];
    a00 += v0.x*u.x + v0.y*u.y + v0.z*u.z + v0.w*u.w;
    a01 += v1.x*u.x + v1.y*u.y + v1.z*u.z + v1.w*u.w;
    a10 += v0.x*w.x + v0.y*w.y + v0.z*w.z + v0.w*w.w;
    a11 += v1.x*w.x + v1.y*w.y + v1.z*w.z + v1.w*w.w;
  }
  float s0  = bg[c0] * rsqrtf(bv[c0] + EPS_);
  float sh0 = bb2[c0] - bm[c0] * s0;
  float s1  = bg[c0+1] * rsqrtf(bv[c0+1] + EPS_);
  float sh1 = bb2[c0+1] - bm[c0+1] * s1;
  const float* xin = branch ? y : x;
  float2 r0 = *(const float2*)(xin + ((size_t)b * C_ + c0) * N_ + p);
  float2 r1 = *(const float2*)(xin + ((size_t)b * C_ + c0 + 1) * N_ + p);
  size_t o = (size_t)z * CN_ + (size_t)c0 * N_ + p;
  *(float2*)(outbase + o)      = make_float2(a00 + r0.x * s0 + sh0,
                                             a01 + r0.y * s0 + sh0);
  *(float2*)(outbase + o + N_) = make_float2(a10 + r1.x * s1 + sh1,
                                             a11 + r1.y * s1 + sh1);
}

// ------ 64-cin conv RAW partial: cin half, 2 couts + 4 px -----------------
// grid (9, C_/2, 8), block 64. z: img = z&3 (layout img*CN), half = z>>2.
__global__ __launch_bounds__(64) void k_convs(
    const float* __restrict__ inA, const float* __restrict__ inB,
    const float* __restrict__ w,
    float* __restrict__ pA, float* __restrict__ pB) {
  int p = blockIdx.x * 256 + threadIdx.x * 4;
  int c0 = blockIdx.y * 2;
  int z = blockIdx.z;
  int img = z & 3, half = z >> 2;
  int yy = p / W_, x0 = p % W_;      // x0 in {0,4,...,44}; row-contained
  const float* ib = (img < 2) ? inA + (size_t)img * CN_
                              : inB + (size_t)(img - 2) * CN_;
  const float* w0r = w + (size_t)c0 * C_ * 9;
  const float* w1r = w0r + (size_t)C_ * 9;
  float a0 = 0.f, a1 = 0.f, a2 = 0.f, a3 = 0.f;
  float b0 = 0.f, b1 = 0.f, b2 = 0.f, b3 = 0.f;
  int ci0 = half * (C_ / 2);
#pragma unroll 2
  for (int ci = ci0; ci < ci0 + C_ / 2; ++ci) {
    const float* ip = ib + ci * N_;
    const float* wp0 = w0r + ci * 9;
    const float* wp1 = w1r + ci * 9;
#pragma unroll
    for (int ky = 0; ky < 3; ++ky) {
      int iyy = yy + ky - 1;
      if ((unsigned)iyy >= (unsigned)H_) continue;
      const float* rp = ip + iyy * W_;
      float4 mid = *(const float4*)(rp + x0);
      float vL = (x0 > 0) ? rp[x0 - 1] : 0.f;
      float vR = (x0 + 4 < W_) ? rp[x0 + 4] : 0.f;
      float u0 = wp0[ky*3], u1 = wp0[ky*3+1], u2 = wp0[ky*3+2];
      float t0 = wp1[ky*3], t1 = wp1[ky*3+1], t2 = wp1[ky*3+2];
      a0 += vL    * u0 + mid.x * u1 + mid.y * u2;
      a1 += mid.x * u0 + mid.y * u1 + mid.z * u2;
      a2 += mid.y * u0 + mid.z * u1 + mid.w * u2;
      a3 += mid.z * u0 + mid.w * u1 + vR    * u2;
      b0 += vL    * t0 + mid.x * t1 + mid.y * t2;
      b1 += mid.x * t0 + mid.y * t1 + mid.z * t2;
      b2 += mid.y * t0 + mid.z * t1 + mid.w * t2;
      b3 += mid.z * t0 + mid.w * t1 + vR    * t2;
    }
  }
  float* ob = (half ? pB : pA) + (size_t)img * CN_ + (size_t)c0 * N_ + p;
  *(float4*)(ob)      = make_float4(a0, a1, a2, a3);
  *(float4*)(ob + N_) = make_float4(b0, b1, b2, b3);
}

// ------ combine halves + bias + bn + relu (conv1 epilogue) ----------------
__global__ void k_combp(const float* __restrict__ pA, const float* __restrict__ pB,
                        const float* __restrict__ cb,
                        const float* __restrict__ g, const float* __restrict__ b2,
                        const float* __restrict__ m, const float* __restrict__ v,
                        float* __restrict__ tA, float* __restrict__ tB) {
  int t = blockIdx.x * 256 + threadIdx.x;
  int p4 = t * 4;
  int n = p4 % N_;
  int c = (p4 / N_) % C_;
  int img = p4 / (int)CN_;
  size_t off = (size_t)img * CN_ + (size_t)c * N_ + n;
  float4 a = *(const float4*)(pA + off);
  float4 d = *(const float4*)(pB + off);
  float s  = g[c] * rsqrtf(v[c] + EPS_);
  float sh = b2[c] - m[c] * s;
  float bias = cb[c];
  float4 r;
  r.x = fmaxf((a.x + d.x + bias) * s + sh, 0.f);
  r.y = fmaxf((a.y + d.y + bias) * s + sh, 0.f);
  r.z = fmaxf((a.z + d.z + bias) * s + sh, 0.f);
  r.w = fmaxf((a.w + d.w + bias) * s + sh, 0.f);
  float* ob = (img < 2) ? tA + off : tB + off - 2 * CN_;
  *(float4*)ob = r;
}

// ------ combine halves + bias + bn + relu + resid (conv2 epilogue) --------
__global__ void k_comb2(float* __restrict__ pA, const float* __restrict__ pB,
                        const float* __restrict__ cb,
                        const float* __restrict__ g, const float* __restrict__ b2,
                        const float* __restrict__ m, const float* __restrict__ v,
                        const float* __restrict__ resid) {
  int t = blockIdx.x * 256 + threadIdx.x;
  int p4 = t * 4;
  int n = p4 % N_;
  int c = (p4 / N_) % C_;
  int img = p4 / (int)CN_;
  size_t off = (size_t)img * CN_ + (size_t)c * N_ + n;
  float4 a = *(const float4*)(pA + off);
  float4 d = *(const float4*)(pB + off);
  float4 rr = *(const float4*)(resid + off);
  float s  = g[c] * rsqrtf(v[c] + EPS_);
  float sh = b2[c] - m[c] * s;
  float bias = cb[c];
  float4 r;
  r.x = fmaxf((a.x + d.x + bias) * s + sh, 0.f) + rr.x;
  r.y = fmaxf((a.y + d.y + bias) * s + sh, 0.f) + rr.y;
  r.z = fmaxf((a.z + d.z + bias) * s + sh, 0.f) + rr.z;
  r.w = fmaxf((a.w + d.w + bias) * s + sh, 0.f) + rr.w;
  *(float4*)(pA + off) = r;
}

// ------ cat = [xo+yo ; xo*yo] + bn2 -> fin, float4 ------------------------
__global__ void k_catbn(const float* __restrict__ o2,
                        const float* __restrict__ g, const float* __restrict__ b2,
                        const float* __restrict__ m, const float* __restrict__ v,
                        float* __restrict__ cat, float* __restrict__ fin,
                        size_t finStride) {
  int t = blockIdx.x * 256 + threadIdx.x;
  int p4 = t * 4;
  int n  = p4 % N_;
  int c2 = (p4 / N_) % (2 * C_);
  int b  = p4 / (2 * C_ * N_);
  int c  = c2 & 63;
  float4 X = *(const float4*)(o2 + (size_t)b * CN_ + (size_t)c * N_ + n);
  float4 Y = *(const float4*)(o2 + (size_t)(2 + b) * CN_ + (size_t)c * N_ + n);
  float4 val;
  if (c2 < C_) val = make_float4(X.x + Y.x, X.y + Y.y, X.z + Y.z, X.w + Y.w);
  else         val = make_float4(X.x * Y.x, X.y * Y.y, X.z * Y.z, X.w * Y.w);
  size_t co = ((size_t)b * 2 * C_ + c2) * N_ + n;
  *(float4*)(cat + co) = val;
  float s  = g[c2] * rsqrtf(v[c2] + EPS_);
  float sh = b2[c2] - m[c2] * s;
  *(float4*)(fin + (size_t)b * finStride + (size_t)c2 * N_ + n) =
      make_float4(val.x * s + sh, val.y * s + sh, val.z * s + sh, val.w * s + sh);
}

// ------ f-branch 3x3 conv partial (64-cin half), 2 couts + 4 px -----------
// grid (9, C_, 2*B_), block 64. z: b = z&1, half = z>>1.
__global__ __launch_bounds__(64) void k_fconvs(
    const float* __restrict__ in, size_t inStride,
    const float* __restrict__ w,
    float* __restrict__ outA, size_t outStrideA,
    float* __restrict__ outB, size_t outStrideB) {
  int p = blockIdx.x * 256 + threadIdx.x * 4;
  int c0 = blockIdx.y * 2;
  int z = blockIdx.z;
  int b = z & 1, half = z >> 1;
  int yy = p / W_, x0 = p % W_;
  const float* ib = in + (size_t)b * inStride;
  const float* w0r = w + (size_t)c0 * (2 * C_) * 9;
  const float* w1r = w0r + (size_t)(2 * C_) * 9;
  float a0 = 0.f, a1 = 0.f, a2 = 0.f, a3 = 0.f;
  float b0 = 0.f, b1 = 0.f, b2 = 0.f, b3 = 0.f;
  int ci0 = half * C_;
#pragma unroll 2
  for (int ci = ci0; ci < ci0 + C_; ++ci) {
    const float* ip = ib + ci * N_;
    const float* wp0 = w0r + ci * 9;
    const float* wp1 = w1r + ci * 9;
#pragma unroll
    for (int ky = 0; ky < 3; ++ky) {
      int iyy = yy + ky - 1;
      if ((unsigned)iyy >= (unsigned)H_) continue;
      const float* rp = ip + iyy * W_;
      float4 mid = *(const float4*)(rp + x0);
      float vL = (x0 > 0) ? rp[x0 - 1] : 0.f;
      float vR = (x0 + 4 < W_) ? rp[x0 + 4] : 0.f;
      float u0 = wp0[ky*3], u1 = wp0[ky*3+1], u2 = wp0[ky*3+2];
      float t0 = wp1[ky*3], t1 = wp1[ky*3+1], t2 = wp1[ky*3+2];
      a0 += vL    * u0 + mid.x * u1 + mid.y * u2;
      a1 += mid.x * u0 + mid.y * u1 + mid.z * u2;
      a2 += mid.y * u0 + mid.z * u1 + mid.w * u2;
      a3 += mid.z * u0 + mid.w * u1 + vR    * u2;
      b0 += vL    * t0 + mid.x * t1 + mid.y * t2;
      b1 += mid.x * t0 + mid.y * t1 + mid.z * t2;
      b2 += mid.y * t0 + mid.z * t1 + mid.w * t2;
      b3 += mid.z * t0 + mid.w * t1 + vR    * t2;
    }
  }
  float* ob = (half ? outB + (size_t)b * outStrideB
                    : outA + (size_t)b * outStrideA);
  size_t o = (size_t)c0 * N_ + p;
  *(float4*)(ob + o)      = make_float4(a0, a1, a2, a3);
  *(float4*)(ob + o + N_) = make_float4(b0, b1, b2, b3);
}

// ------ combine halves + bn + relu, float4 (in-place into A ok) -----------
__global__ void k_comb(const float* __restrict__ pA, size_t strideA,
                       const float* __restrict__ pB, size_t strideB,
                       const float* __restrict__ g, const float* __restrict__ b2,
                       const float* __restrict__ m, const float* __restrict__ v,
                       float* __restrict__ out, size_t outStride) {
  int t = blockIdx.x * 256 + threadIdx.x;
  int p4 = t * 4;
  int n = p4 % N_;
  int c = (p4 / N_) % (2 * C_);
  int b = p4 / (2 * C_ * N_);
  size_t off = (size_t)c * N_ + n;
  float4 a = *(const float4*)(pA + (size_t)b * strideA + off);
  float4 d = *(const float4*)(pB + (size_t)b * strideB + off);
  float s  = g[c] * rsqrtf(v[c] + EPS_);
  float sh = b2[c] - m[c] * s;
  float4 r;
  r.x = fmaxf((a.x + d.x) * s + sh, 0.f);
  r.y = fmaxf((a.y + d.y) * s + sh, 0.f);
  r.z = fmaxf((a.z + d.z) * s + sh, 0.f);
  r.w = fmaxf((a.w + d.w) * s + sh, 0.f);
  *(float4*)(out + (size_t)b * outStride + off) = r;
}

// -------- final v2: 2 couts/block, fused comb(fbn2)+relu + cat add --------
// grid (18, C_, B_), block 64. bn scale/shift precomputed into LDS.
__global__ __launch_bounds__(64) void k_final3(
    const float* __restrict__ pA, size_t strideA,
    const float* __restrict__ pB, size_t strideB,
    const float* __restrict__ g2, const float* __restrict__ b2,
    const float* __restrict__ m2, const float* __restrict__ v2,
    const float* __restrict__ cat,
    const float* __restrict__ w, const float* __restrict__ fb,
    float* __restrict__ out) {
  __shared__ float fsc[2 * C_], fsh[2 * C_];
  for (int j = threadIdx.x; j < 2 * C_; j += 64) {
    float s = g2[j] * rsqrtf(v2[j] + EPS_);
    fsc[j] = s;
    fsh[j] = b2[j] - m2[j] * s;
  }
  __syncthreads();
  int p = blockIdx.x * 128 + threadIdx.x * 2;
  int c0 = blockIdx.y * 2;
  int b = blockIdx.z;
  const float* frA = pA + (size_t)b * strideA;
  const float* frB = pB + (size_t)b * strideB;
  const float* wr0 = w + (size_t)c0 * 2 * C_;
  const float* wr1 = wr0 + 2 * C_;
  float a00 = fb[c0], a01 = a00;
  float a10 = fb[c0 + 1], a11 = a10;
#pragma unroll 4
  for (int j = 0; j < 2 * C_; ++j) {
    float2 fa = *(const float2*)(frA + (size_t)j * N_ + p);
    float2 fd = *(const float2*)(frB + (size_t)j * N_ + p);
    float s = fsc[j], sh = fsh[j];
    float f0 = fmaxf((fa.x + fd.x) * s + sh, 0.f);
    float f1 = fmaxf((fa.y + fd.y) * s + sh, 0.f);
    float wv0 = wr0[j], wv1 = wr1[j];
    a00 += wv0 * f0; a01 += wv0 * f1;
    a10 += wv1 * f0; a11 += wv1 * f1;
  }
  size_t o = ((size_t)b * 2 * C_ + c0) * N_ + p;
  float2 cv0 = *(const float2*)(cat + o);
  float2 cv1 = *(const float2*)(cat + o + N_);
  *(float2*)(out + o)      = make_float2(a00 + cv0.x, a01 + cv0.y);
  *(float2*)(out + o + N_) = make_float2(a10 + cv1.x, a11 + cv1.y);
}

extern "C" void kernel_launch(void* const* d_in, const int* in_sizes, int n_in,
                              void* d_out, int out_size, void* d_ws, size_t ws_size,
                              hipStream_t stream) {
  const float* x       = (const float*)d_in[0];
  const float* y       = (const float*)d_in[1];
  const float* pconv_w = (const float*)d_in[2];
  const float* pconv_b = (const float*)d_in[3];
  const float* bnd_g = (const float*)d_in[4];
  const float* bnd_b = (const float*)d_in[5];
  const float* bnd_m = (const float*)d_in[6];
  const float* bnd_v = (const float*)d_in[7];
  const float* lnx_g = (const float*)d_in[8];
  const float* lnx_b = (const float*)d_in[9];
  const float* lny_g = (const float*)d_in[10];
  const float* lny_b = (const float*)d_in[11];
  const float* lnz_g = (const float*)d_in[12];
  const float* lnz_b = (const float*)d_in[13];
  const float* k_w   = (const float*)d_in[14];
  const float* k_b   = (const float*)d_in[15];
  const float* qv_w  = (const float*)d_in[16];
  const float* qv_b  = (const float*)d_in[17];
  const float* proj_w = (const float*)d_in[18];
  const float* proj_b = (const float*)d_in[19];
  const float* c2w1  = (const float*)d_in[20];
  const float* c2b1  = (const float*)d_in[21];
  const float* c2bn1_g = (const float*)d_in[22];
  const float* c2bn1_b = (const float*)d_in[23];
  const float* c2bn1_m = (const float*)d_in[24];
  const float* c2bn1_v = (const float*)d_in[25];
  const float* c2w2  = (const float*)d_in[26];
  const float* c2b2  = (const float*)d_in[27];
  const float* c2bn2_g = (const float*)d_in[28];
  const float* c2bn2_b = (const float*)d_in[29];
  const float* c2bn2_m = (const float*)d_in[30];
  const float* c2bn2_v = (const float*)d_in[31];
  const float* bn2_g = (const float*)d_in[32];
  const float* bn2_b = (const float*)d_in[33];
  const float* bn2_m = (const float*)d_in[34];
  const float* bn2_v = (const float*)d_in[35];
  const float* f1w   = (const float*)d_in[36];
  const float* fbn1_g = (const float*)d_in[37];
  const float* fbn1_b = (const float*)d_in[38];
  const float* fbn1_m = (const float*)d_in[39];
  const float* fbn1_v = (const float*)d_in[40];
  const float* f2w   = (const float*)d_in[41];
  const float* fbn2_g = (const float*)d_in[42];
  const float* fbn2_b = (const float*)d_in[43];
  const float* fbn2_m = (const float*)d_in[44];
  const float* fbn2_v = (const float*)d_in[45];
  const float* f3w   = (const float*)d_in[46];
  const float* f3b   = (const float*)d_in[47];

  // 8-slot workspace plan:
  //   A: k_pre -> xl(1) yl(2) zl(3)
  //   B: qvk -> bf16: qx|qy(4), k(5 lo), VT(6)
  //   C: attn8 (MFMA) -> att_xo(1) att_yo(2)
  //   D: proj -> xo4(3,4) [img*CN, imgs 0..3]
  //   E1: convs(conv1) raw partials: half0 -> (1,2), half1 -> (5,6)
  //   E2: combp (+bias/bn/relu) -> tmp imgs01 (0), imgs23 (7)
  //   F1: convs(conv2) raw partials from tmp -> (1,2)(5,6)
  //   F2: comb2 (+bias/bn/relu + resid(3,4)) -> o2 in-place (1,2)
  //   G: catbn reads o2(1,2) -> cat(3,4), fin b0->(0), b1->(7) [stride 7S]
  //   H1: fconvs f1: fin(0/7) -> half0 (1,2 stride S), half1 (5,6 stride S)
  //   H2: comb -> (1,2) in-place
  //   H3: fconvs f2: (1,2) -> half0 (5,6), half1 (0/7)
  //   I: final3 reads (5,6)+(0/7), cat(3,4) -> out
  float* ws = (float*)d_ws;
  float* sl0 = ws + 0 * S_;
  float* sl1 = ws + 1 * S_;
  float* sl2 = ws + 2 * S_;
  float* sl3 = ws + 3 * S_;
  float* sl4 = ws + 4 * S_;
  float* sl5 = ws + 5 * S_;
  float* sl7 = ws + 7 * S_;

  // A. fused pconv + bn + ln
  k_pre<<<B_ * N_, 64, 0, stream>>>(x, y, pconv_w, pconv_b,
                                    bnd_g, bnd_b, bnd_m, bnd_v,
                                    lnx_g, lnx_b, lny_g, lny_b, lnz_g, lnz_b,
                                    sl1, sl2, sl3);
  // B. fused qv + kproj -> bf16 attention operands
  u16* qxb = (u16*)sl4;
  u16* qyb = qxb + (size_t)B_ * NH_ * N_ * 8;   // 294912 shorts
  u16* kbf = (u16*)sl5;
  u16* vtb = (u16*)(ws + 6 * S_);
  {
    dim3 g(2304, 1, 3);
    k_qvk<<<g, 256, 0, stream>>>(sl1, sl3, qv_w, qv_b, k_w, k_b,
                                 qxb, qyb, kbf, vtb);
  }
  // C. attention v8 (MFMA) -> att_xo(1), att_yo(2)
  {
    dim3 g(N_ / 16, B_ * NH_);
    k_attn8<<<g, 128, 0, stream>>>(qxb, qyb, kbf, vtb, sl1, sl2);
  }
  // D. proj v2 (2 couts) -> xo4(3,4)
  {
    dim3 g(18, C_ / 2, 2 * B_);
    k_proj2<<<g, 64, 0, stream>>>(sl1, x, y, bnd_g, bnd_b, bnd_m, bnd_v,
                                  proj_w, proj_b, sl3);
  }
  // E. conv1: cin-split raw partials (4 px) + combine epilogue -> tmp(0 / 7)
  {
    dim3 g(9, C_ / 2, 8);
    k_convs<<<g, 64, 0, stream>>>(sl3, sl3 + 2 * CN_, c2w1, sl1, sl5);
    k_combp<<<576, 256, 0, stream>>>(sl1, sl5, c2b1,
        c2bn1_g, c2bn1_b, c2bn1_m, c2bn1_v, sl0, sl7);
  }
  // F. conv2: cin-split raw partials (4 px) + combine(+resid) -> o2(1,2)
  {
    dim3 g(9, C_ / 2, 8);
    k_convs<<<g, 64, 0, stream>>>(sl0, sl7, c2w2, sl1, sl5);
    k_comb2<<<576, 256, 0, stream>>>(sl1, sl5, c2b2,
        c2bn2_g, c2bn2_b, c2bn2_m, c2bn2_v, sl3);
  }
  // G. cat + bn2 -> cat(3,4), fin(0 / 7)
  k_catbn<<<576, 256, 0, stream>>>(sl1, bn2_g, bn2_b, bn2_m, bn2_v,
                                   sl3, sl0, 7 * S_);
  // H. f-branch convs, ci-split, 4 px/thread
  {
    dim3 g(9, C_, 2 * B_);
    k_fconvs<<<g, 64, 0, stream>>>(sl0, 7 * S_, f1w, sl1, S_, sl5, S_);
    k_comb<<<576, 256, 0, stream>>>(sl1, S_, sl5, S_,
                                    fbn1_g, fbn1_b, fbn1_m, fbn1_v, sl1, S_);
    k_fconvs<<<g, 64, 0, stream>>>(sl1, S_, f2w, sl5, S_, sl0, 7 * S_);
  }
  // I. final v2 (2 couts) -> fp32 out
  {
    dim3 g(18, C_, B_);
    k_final3<<<g, 64, 0, stream>>>(sl5, S_, sl0, 7 * S_,
                                   fbn2_g, fbn2_b, fbn2_m, fbn2_v,
                                   sl3, f3w, f3b, (float*)d_out);
  }
}

// Round 3
// 524.059 us; speedup vs baseline: 1.1558x; 1.0076x over previous
//
#include <hip/hip_runtime.h>
#include <hip/hip_bf16.h>

#define B_   2
#define C_   64
#define H_   48
#define W_   48
#define N_   (H_*W_)     // 2304
#define NH_  8
#define HD_  8
#define EPS_ 1e-5f
#define S2_  0.125f      // scale^2 = 1/hd
#define LOG2E_ 1.44269504f
#define FS_  (S2_ * LOG2E_)
#define S_   ((size_t)B_ * C_ * N_)   // 294912 floats per workspace slot
#define CN_  ((size_t)C_ * N_)        // 147456 floats per image

typedef unsigned short u16;
typedef __attribute__((ext_vector_type(8))) short short8v;
typedef __attribute__((ext_vector_type(4))) float f32x4;
union F8 { uint4 u4; short8v s; unsigned int w[4]; };

__device__ __forceinline__ float wsum64(float v) {
#pragma unroll
  for (int o = 32; o > 0; o >>= 1) v += __shfl_xor(v, o, 64);
  return v;
}

__device__ __forceinline__ float ln_val(float t, float g, float b) {
  float mu  = wsum64(t) * (1.0f / 64.0f);
  float d   = t - mu;
  float var = wsum64(d * d) * (1.0f / 64.0f);
  return d * rsqrtf(var + EPS_) * g + b;
}

// round-to-nearest-even f32 -> bf16 (finite inputs only)
__device__ __forceinline__ u16 f2bf(float x) {
  union { float f; unsigned int u; } a; a.f = x;
  unsigned int r = a.u + 0x7fffu + ((a.u >> 16) & 1u);
  return (u16)(r >> 16);
}

// ---- fused 1x1 pconv + BN + 3x LayerNorm; block = one (b,n) row ----------
__global__ __launch_bounds__(64) void k_pre(
    const float* __restrict__ x, const float* __restrict__ y,
    const float* __restrict__ pw, const float* __restrict__ pb,
    const float* g, const float* bb, const float* m, const float* v,
    const float* lnxg, const float* lnxb,
    const float* lnyg, const float* lnyb,
    const float* lnzg, const float* lnzb,
    float* __restrict__ xl, float* __restrict__ yl, float* __restrict__ zl) {
  __shared__ float xs[64], ys[64];
  int row = blockIdx.x;            // b*N + n
  int c = threadIdx.x;
  int b = row / N_, n = row % N_;
  float xv = x[(size_t)(b * C_ + c) * N_ + n];
  float yv = y[(size_t)(b * C_ + c) * N_ + n];
  xs[c] = xv; ys[c] = yv;
  __syncthreads();
  const float4* wr  = (const float4*)(pw + (size_t)c * 2 * C_);
  const float4* xs4 = (const float4*)xs;
  const float4* ys4 = (const float4*)ys;
  float acc = pb[c];
#pragma unroll
  for (int t = 0; t < 16; ++t) {
    float4 a = xs4[t], wv = wr[t];
    acc += a.x * wv.x + a.y * wv.y + a.z * wv.z + a.w * wv.w;
  }
#pragma unroll
  for (int t = 0; t < 16; ++t) {
    float4 a = ys4[t], wv = wr[16 + t];
    acc += a.x * wv.x + a.y * wv.y + a.z * wv.z + a.w * wv.w;
  }
  float s  = g[c] * rsqrtf(v[c] + EPS_);
  float sh = bb[c] - m[c] * s;
  float tx = xv * s + sh;
  xl[(size_t)row * C_ + c] = ln_val(tx, lnxg[c], lnxb[c]);
  float ty = yv * s + sh;
  yl[(size_t)row * C_ + c] = ln_val(ty, lnyg[c], lnyb[c]);
  float tz = acc * s + sh;
  zl[(size_t)row * C_ + c] = ln_val(tz, lnzg[c], lnzb[c]);
}

// ------------- fused qv (both branches) + k projection --------------------
//   qxb [bh][n][8]  (scale FS_ folded in), qyb [bh][n][8]
//   kbf [bh][n][8]
//   vt  [bh][16][N]  rows 0-7 = Vx dims, rows 8-15 = Vy dims (transposed)
__global__ void k_qvk(const float* __restrict__ lnb, const float* __restrict__ zl,
                      const float* __restrict__ qvw, const float* __restrict__ qvb,
                      const float* __restrict__ kw, const float* __restrict__ kb,
                      u16* __restrict__ qxb, u16* __restrict__ qyb,
                      u16* __restrict__ kbf, u16* __restrict__ vt) {
  int z = blockIdx.z;
  if (z < 2) {
    int idx = blockIdx.x * 256 + threadIdx.x;   // B*N*128
    int j = idx & 127;
    int row = idx >> 7;
    int b = row / N_, n = row % N_;
    const float4* ir = (const float4*)(lnb + z * S_ + (size_t)row * C_);
    const float4* wr = (const float4*)(qvw + (size_t)j * C_);
    float acc = qvb[j];
#pragma unroll
    for (int t = 0; t < 16; ++t) {
      float4 a = ir[t], wv = wr[t];
      acc += a.x * wv.x + a.y * wv.y + a.z * wv.z + a.w * wv.w;
    }
    int jj = j & 63;
    int h = jj >> 3, d = jj & 7;
    int bh = b * NH_ + h;
    if (j < C_) {   // q
      float val = (z == 0) ? acc * FS_ : acc;
      u16* dst = (z == 0) ? qxb : qyb;
      dst[((size_t)bh * N_ + n) * 8 + d] = f2bf(val);
    } else {        // v (transposed store)
      vt[((size_t)bh * 16 + z * 8 + d) * N_ + n] = f2bf(acc);
    }
  } else {
    if (blockIdx.x >= 1152) return;
    int idx = blockIdx.x * 256 + threadIdx.x;   // B*N*64
    int j = idx & 63;
    int row = idx >> 6;
    int b = row / N_, n = row % N_;
    const float4* ir = (const float4*)(zl + (size_t)row * C_);
    const float4* wr = (const float4*)(kw + (size_t)j * C_);
    float acc = kb[j];
#pragma unroll
    for (int t = 0; t < 16; ++t) {
      float4 a = ir[t], wv = wr[t];
      acc += a.x * wv.x + a.y * wv.y + a.z * wv.z + a.w * wv.w;
    }
    int h = j >> 3, d = j & 7;
    kbf[((size_t)(b * NH_ + h) * N_ + n) * 8 + d] = f2bf(acc);
  }
}

// ---------------- attention v8: MFMA flash, 16-q tile, dual-branch --------
__global__ __launch_bounds__(128, 5) void k_attn8(
    const u16* __restrict__ qx, const u16* __restrict__ qy,
    const u16* __restrict__ kk, const u16* __restrict__ vt,
    float* __restrict__ outx, float* __restrict__ outy) {
  __shared__ float sAcc[2][4][64];
  __shared__ float sL[2][16];
  int qt = blockIdx.x, bh = blockIdx.y;
  int tid = threadIdx.x;
  int lane = tid & 63;
  int wave = tid >> 6;
  int l15 = lane & 15;
  int q0 = qt * 16;

  F8 qxf, qyf;
  size_t qoff = ((size_t)bh * N_ + q0 + l15) * 8;
  qxf.u4 = *(const uint4*)(qx + qoff);
  qyf.u4 = *(const uint4*)(qy + qoff);
  if (lane >= 16) {
    qxf.u4 = make_uint4(0u, 0u, 0u, 0u);
    qyf.u4 = make_uint4(0u, 0u, 0u, 0u);
  }

  int key0 = wave * (N_ / 2);
  const uint4* kp = (const uint4*)(kk + (size_t)bh * N_ * 8) + key0 + l15;
  const uint4* vp = (const uint4*)(vt + ((size_t)bh * 16 + l15) * N_ + key0)
                    + (lane >> 4);
  int addr0 = (((lane >> 4) & 1) * 32 + l15) * 4;
  int addr1 = addr0 + 64;
  int thi = lane >> 5;

  f32x4 acc = {0.f, 0.f, 0.f, 0.f};
  const f32x4 z4 = {0.f, 0.f, 0.f, 0.f};
  float lsum = 0.f;

  F8 ka, kb2, vf;
  ka.u4 = kp[0]; kb2.u4 = kp[16]; vf.u4 = *vp;
  for (int c = 0; c < 36; ++c) {
    F8 kaC = ka, kbC = kb2, vfC = vf;
    kp += 32; vp += 4;
    ka.u4 = kp[0]; kb2.u4 = kp[16]; vf.u4 = *vp;   // prefetch next chunk

    f32x4 s1a = __builtin_amdgcn_mfma_f32_16x16x32_bf16(kaC.s, qxf.s, z4, 0, 0, 0);
    f32x4 s2a = __builtin_amdgcn_mfma_f32_16x16x32_bf16(kaC.s, qyf.s, z4, 0, 0, 0);
    f32x4 s1b = __builtin_amdgcn_mfma_f32_16x16x32_bf16(kbC.s, qxf.s, z4, 0, 0, 0);
    f32x4 s2b = __builtin_amdgcn_mfma_f32_16x16x32_bf16(kbC.s, qyf.s, z4, 0, 0, 0);

    float p00 = exp2f(s1a[0] * s2a[0]), p01 = exp2f(s1a[1] * s2a[1]);
    float p02 = exp2f(s1a[2] * s2a[2]), p03 = exp2f(s1a[3] * s2a[3]);
    float p10 = exp2f(s1b[0] * s2b[0]), p11 = exp2f(s1b[1] * s2b[1]);
    float p12 = exp2f(s1b[2] * s2b[2]), p13 = exp2f(s1b[3] * s2b[3]);
    lsum += ((p00 + p01) + (p02 + p03)) + ((p10 + p11) + (p12 + p13));

    unsigned int pk00, pk10, pk01, pk11;
    asm("v_cvt_pk_bf16_f32 %0, %1, %2" : "=v"(pk00) : "v"(p00), "v"(p01));
    asm("v_cvt_pk_bf16_f32 %0, %1, %2" : "=v"(pk10) : "v"(p02), "v"(p03));
    asm("v_cvt_pk_bf16_f32 %0, %1, %2" : "=v"(pk01) : "v"(p10), "v"(p11));
    asm("v_cvt_pk_bf16_f32 %0, %1, %2" : "=v"(pk11) : "v"(p12), "v"(p13));

    int b00 = __builtin_amdgcn_ds_bpermute(addr0, (int)pk00);
    int b01 = __builtin_amdgcn_ds_bpermute(addr0, (int)pk01);
    int b10 = __builtin_amdgcn_ds_bpermute(addr0, (int)pk10);
    int b11 = __builtin_amdgcn_ds_bpermute(addr0, (int)pk11);
    int c00 = __builtin_amdgcn_ds_bpermute(addr1, (int)pk00);
    int c01 = __builtin_amdgcn_ds_bpermute(addr1, (int)pk01);
    int c10 = __builtin_amdgcn_ds_bpermute(addr1, (int)pk10);
    int c11 = __builtin_amdgcn_ds_bpermute(addr1, (int)pk11);

    F8 pf;
    pf.w[0] = (unsigned int)(thi ? b01 : b00);
    pf.w[1] = (unsigned int)(thi ? b11 : b10);
    pf.w[2] = (unsigned int)(thi ? c01 : c00);
    pf.w[3] = (unsigned int)(thi ? c11 : c10);
    acc = __builtin_amdgcn_mfma_f32_16x16x32_bf16(pf.s, vfC.s, acc, 0, 0, 0);
  }

  lsum += __shfl_xor(lsum, 16, 64);
  lsum += __shfl_xor(lsum, 32, 64);
  if (lane < 16) sL[wave][lane] = lsum;
#pragma unroll
  for (int r = 0; r < 4; ++r) sAcc[wave][r][lane] = acc[r];
  __syncthreads();
  if (wave == 0) {
    float Linv = 1.f / (sL[0][l15] + sL[1][l15]);
    int b = bh >> 3, h = bh & 7;
    int d = l15 & 7;
    float* ob = (l15 < 8) ? outx : outy;
    size_t cbase = (size_t)b * N_ * C_ + (size_t)h * 8 + d;
#pragma unroll
    for (int r = 0; r < 4; ++r) {
      int qrow = 4 * (lane >> 4) + r;
      float li = __shfl(Linv, qrow, 64);
      float a = sAcc[0][r][lane] + sAcc[1][r][lane];
      ob[cbase + (size_t)(q0 + qrow) * C_] = a * li;
    }
  }
}

// -------- proj v2: 2 couts + 2 px per thread (att rows shared) ------------
__global__ __launch_bounds__(64) void k_proj2(
    const float* __restrict__ attbase,
    const float* __restrict__ x, const float* __restrict__ y,
    const float* bg, const float* bb2, const float* bm, const float* bv,
    const float* __restrict__ pw, const float* __restrict__ pbias,
    float* __restrict__ outbase) {
  int p = blockIdx.x * 128 + threadIdx.x * 2;
  int c0 = blockIdx.y * 2;
  int z = blockIdx.z;
  int branch = z >> 1, b = z & 1;
  const float* att = attbase + branch * S_ + (size_t)b * N_ * C_;
  const float4* w0 = (const float4*)(pw + (size_t)c0 * C_);
  const float4* w1 = (const float4*)(pw + (size_t)(c0 + 1) * C_);
  const float4* ar0 = (const float4*)(att + (size_t)p * C_);
  const float4* ar1 = (const float4*)(att + (size_t)(p + 1) * C_);
  float bias0 = pbias[c0], bias1 = pbias[c0 + 1];
  float a00 = bias0, a01 = bias0, a10 = bias1, a11 = bias1;
#pragma unroll
  for (int t = 0; t < 16; ++t) {
    float4 v0 = ar0[t], v1 = ar1[t];
    float4 u = w0[t], w = w1[t];
    a00 += v0.x*u.x + v0.y*u.y + v0.z*u.z + v0.w*u.w;
    a01 += v1.x*u.x + v1.y*u.y + v1.z*u.z + v1.w*u.w;
    a10 += v0.x*w.x + v0.y*w.y + v0.z*w.z + v0.w*w.w;
    a11 += v1.x*w.x + v1.y*w.y + v1.z*w.z + v1.w*w.w;
  }
  float s0  = bg[c0] * rsqrtf(bv[c0] + EPS_);
  float sh0 = bb2[c0] - bm[c0] * s0;
  float s1  = bg[c0+1] * rsqrtf(bv[c0+1] + EPS_);
  float sh1 = bb2[c0+1] - bm[c0+1] * s1;
  const float* xin = branch ? y : x;
  float2 r0 = *(const float2*)(xin + ((size_t)b * C_ + c0) * N_ + p);
  float2 r1 = *(const float2*)(xin + ((size_t)b * C_ + c0 + 1) * N_ + p);
  size_t o = (size_t)z * CN_ + (size_t)c0 * N_ + p;
  *(float2*)(outbase + o)      = make_float2(a00 + r0.x * s0 + sh0,
                                             a01 + r0.y * s0 + sh0);
  *(float2*)(outbase + o + N_) = make_float2(a10 + r1.x * s1 + sh1,
                                             a11 + r1.y * s1 + sh1);
}

// ===== conv core v2: LDS-staged weights, hoisted rows, prefetch-friendly ==
// Per thread: 4 px (float4-aligned, row-contained) x 2 couts.
// wlds layout: [ci][ky][j][kx] flat = ci*18 + ky*6 + j*3 + kx.
template<int CIN, int CIPB>
__device__ __forceinline__ void conv_core2(
    const float* __restrict__ ib, const float* __restrict__ w,
    int c0, int ci0, int p, int tid, float* wlds,
    float4& A0, float4& A1) {
  for (int t = tid; t < CIPB * 18; t += 64) {
    int ci = t / 18, r = t - ci * 18;
    int ky = r / 6, q = r - ky * 6;
    int j = q / 3, kx = q - j * 3;
    wlds[t] = w[((size_t)(c0 + j) * CIN + (ci0 + ci)) * 9 + ky * 3 + kx];
  }
  __syncthreads();
  int yy = p / W_, x0 = p - yy * W_;     // x0 in {0,4,...,44}
  bool okL = x0 > 0, okR = x0 + 4 < W_;
  bool ok0 = yy > 0, ok2 = yy < H_ - 1;
  int off0 = (yy - 1) * W_ + x0;
  const float* bp = ib + (size_t)ci0 * N_;
  const float* wl = wlds;
#pragma unroll 2
  for (int ci = 0; ci < CIPB; ++ci, bp += N_, wl += 18) {
    float4 m0, m1, m2;
    float l0, l1, l2, r0, r1, r2;
    if (ok0) {
      m0 = *(const float4*)(bp + off0);
      l0 = okL ? bp[off0 - 1] : 0.f;
      r0 = okR ? bp[off0 + 4] : 0.f;
    } else { m0 = make_float4(0.f,0.f,0.f,0.f); l0 = 0.f; r0 = 0.f; }
    m1 = *(const float4*)(bp + off0 + W_);
    l1 = okL ? bp[off0 + W_ - 1] : 0.f;
    r1 = okR ? bp[off0 + W_ + 4] : 0.f;
    if (ok2) {
      m2 = *(const float4*)(bp + off0 + 2 * W_);
      l2 = okL ? bp[off0 + 2 * W_ - 1] : 0.f;
      r2 = okR ? bp[off0 + 2 * W_ + 4] : 0.f;
    } else { m2 = make_float4(0.f,0.f,0.f,0.f); l2 = 0.f; r2 = 0.f; }

#define CONV_ROW(MM, LL, RR, KY)                                          \
    {                                                                     \
      float u0 = wl[(KY)*6+0], u1 = wl[(KY)*6+1], u2 = wl[(KY)*6+2];      \
      float t0 = wl[(KY)*6+3], t1 = wl[(KY)*6+4], t2 = wl[(KY)*6+5];      \
      A0.x += LL   * u0 + MM.x * u1 + MM.y * u2;                          \
      A0.y += MM.x * u0 + MM.y * u1 + MM.z * u2;                          \
      A0.z += MM.y * u0 + MM.z * u1 + MM.w * u2;                          \
      A0.w += MM.z * u0 + MM.w * u1 + RR   * u2;                          \
      A1.x += LL   * t0 + MM.x * t1 + MM.y * t2;                          \
      A1.y += MM.x * t0 + MM.y * t1 + MM.z * t2;                          \
      A1.z += MM.y * t0 + MM.z * t1 + MM.w * t2;                          \
      A1.w += MM.z * t0 + MM.w * t1 + RR   * t2;                          \
    }
    CONV_ROW(m0, l0, r0, 0)
    CONV_ROW(m1, l1, r1, 1)
    CONV_ROW(m2, l2, r2, 2)
#undef CONV_ROW
  }
}

// ------ 64-cin conv RAW partial: cin half, 2 couts + 4 px -----------------
// grid (9, C_/2, 8), block 64. z: img = z&3 (layout img*CN), half = z>>2.
__global__ __launch_bounds__(64) void k_convs(
    const float* __restrict__ inA, const float* __restrict__ inB,
    const float* __restrict__ w,
    float* __restrict__ pA, float* __restrict__ pB) {
  __shared__ float wlds[(C_/2) * 18];
  int p = blockIdx.x * 256 + threadIdx.x * 4;
  int c0 = blockIdx.y * 2;
  int z = blockIdx.z;
  int img = z & 3, half = z >> 2;
  const float* ib = (img < 2) ? inA + (size_t)img * CN_
                              : inB + (size_t)(img - 2) * CN_;
  float4 A0 = make_float4(0.f,0.f,0.f,0.f);
  float4 A1 = make_float4(0.f,0.f,0.f,0.f);
  conv_core2<C_, C_/2>(ib, w, c0, half * (C_/2), p, threadIdx.x, wlds, A0, A1);
  float* ob = (half ? pB : pA) + (size_t)img * CN_ + (size_t)c0 * N_ + p;
  *(float4*)(ob)      = A0;
  *(float4*)(ob + N_) = A1;
}

// ------ combine halves + bias + bn + relu (conv1 epilogue) ----------------
__global__ void k_combp(const float* __restrict__ pA, const float* __restrict__ pB,
                        const float* __restrict__ cb,
                        const float* __restrict__ g, const float* __restrict__ b2,
                        const float* __restrict__ m, const float* __restrict__ v,
                        float* __restrict__ tA, float* __restrict__ tB) {
  int t = blockIdx.x * 256 + threadIdx.x;
  int p4 = t * 4;
  int n = p4 % N_;
  int c = (p4 / N_) % C_;
  int img = p4 / (int)CN_;
  size_t off = (size_t)img * CN_ + (size_t)c * N_ + n;
  float4 a = *(const float4*)(pA + off);
  float4 d = *(const float4*)(pB + off);
  float s  = g[c] * rsqrtf(v[c] + EPS_);
  float sh = b2[c] - m[c] * s;
  float bias = cb[c];
  float4 r;
  r.x = fmaxf((a.x + d.x + bias) * s + sh, 0.f);
  r.y = fmaxf((a.y + d.y + bias) * s + sh, 0.f);
  r.z = fmaxf((a.z + d.z + bias) * s + sh, 0.f);
  r.w = fmaxf((a.w + d.w + bias) * s + sh, 0.f);
  float* ob = (img < 2) ? tA + off : tB + off - 2 * CN_;
  *(float4*)ob = r;
}

// ------ combine halves + bias + bn + relu + resid (conv2 epilogue) --------
__global__ void k_comb2(float* __restrict__ pA, const float* __restrict__ pB,
                        const float* __restrict__ cb,
                        const float* __restrict__ g, const float* __restrict__ b2,
                        const float* __restrict__ m, const float* __restrict__ v,
                        const float* __restrict__ resid) {
  int t = blockIdx.x * 256 + threadIdx.x;
  int p4 = t * 4;
  int n = p4 % N_;
  int c = (p4 / N_) % C_;
  int img = p4 / (int)CN_;
  size_t off = (size_t)img * CN_ + (size_t)c * N_ + n;
  float4 a = *(const float4*)(pA + off);
  float4 d = *(const float4*)(pB + off);
  float4 rr = *(const float4*)(resid + off);
  float s  = g[c] * rsqrtf(v[c] + EPS_);
  float sh = b2[c] - m[c] * s;
  float bias = cb[c];
  float4 r;
  r.x = fmaxf((a.x + d.x + bias) * s + sh, 0.f) + rr.x;
  r.y = fmaxf((a.y + d.y + bias) * s + sh, 0.f) + rr.y;
  r.z = fmaxf((a.z + d.z + bias) * s + sh, 0.f) + rr.z;
  r.w = fmaxf((a.w + d.w + bias) * s + sh, 0.f) + rr.w;
  *(float4*)(pA + off) = r;
}

// ------ cat = [xo+yo ; xo*yo] + bn2 -> fin, float4 ------------------------
__global__ void k_catbn(const float* __restrict__ o2,
                        const float* __restrict__ g, const float* __restrict__ b2,
                        const float* __restrict__ m, const float* __restrict__ v,
                        float* __restrict__ cat, float* __restrict__ fin,
                        size_t finStride) {
  int t = blockIdx.x * 256 + threadIdx.x;
  int p4 = t * 4;
  int n  = p4 % N_;
  int c2 = (p4 / N_) % (2 * C_);
  int b  = p4 / (2 * C_ * N_);
  int c  = c2 & 63;
  float4 X = *(const float4*)(o2 + (size_t)b * CN_ + (size_t)c * N_ + n);
  float4 Y = *(const float4*)(o2 + (size_t)(2 + b) * CN_ + (size_t)c * N_ + n);
  float4 val;
  if (c2 < C_) val = make_float4(X.x + Y.x, X.y + Y.y, X.z + Y.z, X.w + Y.w);
  else         val = make_float4(X.x * Y.x, X.y * Y.y, X.z * Y.z, X.w * Y.w);
  size_t co = ((size_t)b * 2 * C_ + c2) * N_ + n;
  *(float4*)(cat + co) = val;
  float s  = g[c2] * rsqrtf(v[c2] + EPS_);
  float sh = b2[c2] - m[c2] * s;
  *(float4*)(fin + (size_t)b * finStride + (size_t)c2 * N_ + n) =
      make_float4(val.x * s + sh, val.y * s + sh, val.z * s + sh, val.w * s + sh);
}

// ------ f-branch 3x3 conv partial (64-cin half), 2 couts + 4 px -----------
// grid (9, C_, 2*B_), block 64. z: b = z&1, half = z>>1.
__global__ __launch_bounds__(64) void k_fconvs(
    const float* __restrict__ in, size_t inStride,
    const float* __restrict__ w,
    float* __restrict__ outA, size_t outStrideA,
    float* __restrict__ outB, size_t outStrideB) {
  __shared__ float wlds[C_ * 18];
  int p = blockIdx.x * 256 + threadIdx.x * 4;
  int c0 = blockIdx.y * 2;
  int z = blockIdx.z;
  int b = z & 1, half = z >> 1;
  const float* ib = in + (size_t)b * inStride;
  float4 A0 = make_float4(0.f,0.f,0.f,0.f);
  float4 A1 = make_float4(0.f,0.f,0.f,0.f);
  conv_core2<2*C_, C_>(ib, w, c0, half * C_, p, threadIdx.x, wlds, A0, A1);
  float* ob = (half ? outB + (size_t)b * outStrideB
                    : outA + (size_t)b * outStrideA)
              + (size_t)c0 * N_ + p;
  *(float4*)(ob)      = A0;
  *(float4*)(ob + N_) = A1;
}

// ------ combine halves + bn + relu, float4 (in-place into A ok) -----------
__global__ void k_comb(const float* __restrict__ pA, size_t strideA,
                       const float* __restrict__ pB, size_t strideB,
                       const float* __restrict__ g, const float* __restrict__ b2,
                       const float* __restrict__ m, const float* __restrict__ v,
                       float* __restrict__ out, size_t outStride) {
  int t = blockIdx.x * 256 + threadIdx.x;
  int p4 = t * 4;
  int n = p4 % N_;
  int c = (p4 / N_) % (2 * C_);
  int b = p4 / (2 * C_ * N_);
  size_t off = (size_t)c * N_ + n;
  float4 a = *(const float4*)(pA + (size_t)b * strideA + off);
  float4 d = *(const float4*)(pB + (size_t)b * strideB + off);
  float s  = g[c] * rsqrtf(v[c] + EPS_);
  float sh = b2[c] - m[c] * s;
  float4 r;
  r.x = fmaxf((a.x + d.x) * s + sh, 0.f);
  r.y = fmaxf((a.y + d.y) * s + sh, 0.f);
  r.z = fmaxf((a.z + d.z) * s + sh, 0.f);
  r.w = fmaxf((a.w + d.w) * s + sh, 0.f);
  *(float4*)(out + (size_t)b * outStride + off) = r;
}

// -------- final v2: 2 couts/block, fused comb(fbn2)+relu + cat add --------
__global__ __launch_bounds__(64) void k_final3(
    const float* __restrict__ pA, size_t strideA,
    const float* __restrict__ pB, size_t strideB,
    const float* __restrict__ g2, const float* __restrict__ b2,
    const float* __restrict__ m2, const float* __restrict__ v2,
    const float* __restrict__ cat,
    const float* __restrict__ w, const float* __restrict__ fb,
    float* __restrict__ out) {
  __shared__ float fsc[2 * C_], fsh[2 * C_];
  for (int j = threadIdx.x; j < 2 * C_; j += 64) {
    float s = g2[j] * rsqrtf(v2[j] + EPS_);
    fsc[j] = s;
    fsh[j] = b2[j] - m2[j] * s;
  }
  __syncthreads();
  int p = blockIdx.x * 128 + threadIdx.x * 2;
  int c0 = blockIdx.y * 2;
  int b = blockIdx.z;
  const float* frA = pA + (size_t)b * strideA;
  const float* frB = pB + (size_t)b * strideB;
  const float* wr0 = w + (size_t)c0 * 2 * C_;
  const float* wr1 = wr0 + 2 * C_;
  float a00 = fb[c0], a01 = a00;
  float a10 = fb[c0 + 1], a11 = a10;
#pragma unroll 4
  for (int j = 0; j < 2 * C_; ++j) {
    float2 fa = *(const float2*)(frA + (size_t)j * N_ + p);
    float2 fd = *(const float2*)(frB + (size_t)j * N_ + p);
    float s = fsc[j], sh = fsh[j];
    float f0 = fmaxf((fa.x + fd.x) * s + sh, 0.f);
    float f1 = fmaxf((fa.y + fd.y) * s + sh, 0.f);
    float wv0 = wr0[j], wv1 = wr1[j];
    a00 += wv0 * f0; a01 += wv0 * f1;
    a10 += wv1 * f0; a11 += wv1 * f1;
  }
  size_t o = ((size_t)b * 2 * C_ + c0) * N_ + p;
  float2 cv0 = *(const float2*)(cat + o);
  float2 cv1 = *(const float2*)(cat + o + N_);
  *(float2*)(out + o)      = make_float2(a00 + cv0.x, a01 + cv0.y);
  *(float2*)(out + o + N_) = make_float2(a10 + cv1.x, a11 + cv1.y);
}

extern "C" void kernel_launch(void* const* d_in, const int* in_sizes, int n_in,
                              void* d_out, int out_size, void* d_ws, size_t ws_size,
                              hipStream_t stream) {
  const float* x       = (const float*)d_in[0];
  const float* y       = (const float*)d_in[1];
  const float* pconv_w = (const float*)d_in[2];
  const float* pconv_b = (const float*)d_in[3];
  const float* bnd_g = (const float*)d_in[4];
  const float* bnd_b = (const float*)d_in[5];
  const float* bnd_m = (const float*)d_in[6];
  const float* bnd_v = (const float*)d_in[7];
  const float* lnx_g = (const float*)d_in[8];
  const float* lnx_b = (const float*)d_in[9];
  const float* lny_g = (const float*)d_in[10];
  const float* lny_b = (const float*)d_in[11];
  const float* lnz_g = (const float*)d_in[12];
  const float* lnz_b = (const float*)d_in[13];
  const float* k_w   = (const float*)d_in[14];
  const float* k_b   = (const float*)d_in[15];
  const float* qv_w  = (const float*)d_in[16];
  const float* qv_b  = (const float*)d_in[17];
  const float* proj_w = (const float*)d_in[18];
  const float* proj_b = (const float*)d_in[19];
  const float* c2w1  = (const float*)d_in[20];
  const float* c2b1  = (const float*)d_in[21];
  const float* c2bn1_g = (const float*)d_in[22];
  const float* c2bn1_b = (const float*)d_in[23];
  const float* c2bn1_m = (const float*)d_in[24];
  const float* c2bn1_v = (const float*)d_in[25];
  const float* c2w2  = (const float*)d_in[26];
  const float* c2b2  = (const float*)d_in[27];
  const float* c2bn2_g = (const float*)d_in[28];
  const float* c2bn2_b = (const float*)d_in[29];
  const float* c2bn2_m = (const float*)d_in[30];
  const float* c2bn2_v = (const float*)d_in[31];
  const float* bn2_g = (const float*)d_in[32];
  const float* bn2_b = (const float*)d_in[33];
  const float* bn2_m = (const float*)d_in[34];
  const float* bn2_v = (const float*)d_in[35];
  const float* f1w   = (const float*)d_in[36];
  const float* fbn1_g = (const float*)d_in[37];
  const float* fbn1_b = (const float*)d_in[38];
  const float* fbn1_m = (const float*)d_in[39];
  const float* fbn1_v = (const float*)d_in[40];
  const float* f2w   = (const float*)d_in[41];
  const float* fbn2_g = (const float*)d_in[42];
  const float* fbn2_b = (const float*)d_in[43];
  const float* fbn2_m = (const float*)d_in[44];
  const float* fbn2_v = (const float*)d_in[45];
  const float* f3w   = (const float*)d_in[46];
  const float* f3b   = (const float*)d_in[47];

  float* ws = (float*)d_ws;
  float* sl0 = ws + 0 * S_;
  float* sl1 = ws + 1 * S_;
  float* sl2 = ws + 2 * S_;
  float* sl3 = ws + 3 * S_;
  float* sl4 = ws + 4 * S_;
  float* sl5 = ws + 5 * S_;
  float* sl7 = ws + 7 * S_;

  // A. fused pconv + bn + ln
  k_pre<<<B_ * N_, 64, 0, stream>>>(x, y, pconv_w, pconv_b,
                                    bnd_g, bnd_b, bnd_m, bnd_v,
                                    lnx_g, lnx_b, lny_g, lny_b, lnz_g, lnz_b,
                                    sl1, sl2, sl3);
  // B. fused qv + kproj -> bf16 attention operands
  u16* qxb = (u16*)sl4;
  u16* qyb = qxb + (size_t)B_ * NH_ * N_ * 8;
  u16* kbf = (u16*)sl5;
  u16* vtb = (u16*)(ws + 6 * S_);
  {
    dim3 g(2304, 1, 3);
    k_qvk<<<g, 256, 0, stream>>>(sl1, sl3, qv_w, qv_b, k_w, k_b,
                                 qxb, qyb, kbf, vtb);
  }
  // C. attention v8 (MFMA) -> att_xo(1), att_yo(2)
  {
    dim3 g(N_ / 16, B_ * NH_);
    k_attn8<<<g, 128, 0, stream>>>(qxb, qyb, kbf, vtb, sl1, sl2);
  }
  // D. proj v2 (2 couts) -> xo4(3,4)
  {
    dim3 g(18, C_ / 2, 2 * B_);
    k_proj2<<<g, 64, 0, stream>>>(sl1, x, y, bnd_g, bnd_b, bnd_m, bnd_v,
                                  proj_w, proj_b, sl3);
  }
  // E. conv1: cin-split raw partials (4 px) + combine epilogue -> tmp(0 / 7)
  {
    dim3 g(9, C_ / 2, 8);
    k_convs<<<g, 64, 0, stream>>>(sl3, sl3 + 2 * CN_, c2w1, sl1, sl5);
    k_combp<<<576, 256, 0, stream>>>(sl1, sl5, c2b1,
        c2bn1_g, c2bn1_b, c2bn1_m, c2bn1_v, sl0, sl7);
  }
  // F. conv2: cin-split raw partials (4 px) + combine(+resid) -> o2(1,2)
  {
    dim3 g(9, C_ / 2, 8);
    k_convs<<<g, 64, 0, stream>>>(sl0, sl7, c2w2, sl1, sl5);
    k_comb2<<<576, 256, 0, stream>>>(sl1, sl5, c2b2,
        c2bn2_g, c2bn2_b, c2bn2_m, c2bn2_v, sl3);
  }
  // G. cat + bn2 -> cat(3,4), fin(0 / 7)
  k_catbn<<<576, 256, 0, stream>>>(sl1, bn2_g, bn2_b, bn2_m, bn2_v,
                                   sl3, sl0, 7 * S_);
  // H. f-branch convs, ci-split, 4 px/thread
  {
    dim3 g(9, C_, 2 * B_);
    k_fconvs<<<g, 64, 0, stream>>>(sl0, 7 * S_, f1w, sl1, S_, sl5, S_);
    k_comb<<<576, 256, 0, stream>>>(sl1, S_, sl5, S_,
                                    fbn1_g, fbn1_b, fbn1_m, fbn1_v, sl1, S_);
    k_fconvs<<<g, 64, 0, stream>>>(sl1, S_, f2w, sl5, S_, sl0, 7 * S_);
  }
  // I. final v2 (2 couts) -> fp32 out
  {
    dim3 g(18, C_, B_);
    k_final3<<<g, 64, 0, stream>>>(sl5, S_, sl0, 7 * S_,
                                   fbn2_g, fbn2_b, fbn2_m, fbn2_v,
                                   sl3, f3w, f3b, (float*)d_out);
  }
}

// Round 4
// 449.827 us; speedup vs baseline: 1.3466x; 1.1650x over previous
//
#include <hip/hip_runtime.h>
#include <hip/hip_bf16.h>

#define B_   2
#define C_   64
#define H_   48
#define W_   48
#define N_   (H_*W_)     // 2304
#define NH_  8
#define HD_  8
#define EPS_ 1e-5f
#define S2_  0.125f      // scale^2 = 1/hd
#define LOG2E_ 1.44269504f
#define FS_  (S2_ * LOG2E_)
#define S_   ((size_t)B_ * C_ * N_)   // 294912 floats per workspace slot
#define CN_  ((size_t)C_ * N_)        // 147456 floats per image

typedef unsigned short u16;
typedef __attribute__((ext_vector_type(8))) short short8v;
typedef __attribute__((ext_vector_type(4))) float f32x4;
union F8 { uint4 u4; short8v s; unsigned int w[4]; };

__device__ __forceinline__ float wsum64(float v) {
#pragma unroll
  for (int o = 32; o > 0; o >>= 1) v += __shfl_xor(v, o, 64);
  return v;
}

__device__ __forceinline__ float ln_val(float t, float g, float b) {
  float mu  = wsum64(t) * (1.0f / 64.0f);
  float d   = t - mu;
  float var = wsum64(d * d) * (1.0f / 64.0f);
  return d * rsqrtf(var + EPS_) * g + b;
}

// round-to-nearest-even f32 -> bf16 (finite inputs only)
__device__ __forceinline__ u16 f2bf(float x) {
  union { float f; unsigned int u; } a; a.f = x;
  unsigned int r = a.u + 0x7fffu + ((a.u >> 16) & 1u);
  return (u16)(r >> 16);
}

// ---- fused 1x1 pconv + BN + 3x LayerNorm; block = one (b,n) row ----------
__global__ __launch_bounds__(64) void k_pre(
    const float* __restrict__ x, const float* __restrict__ y,
    const float* __restrict__ pw, const float* __restrict__ pb,
    const float* g, const float* bb, const float* m, const float* v,
    const float* lnxg, const float* lnxb,
    const float* lnyg, const float* lnyb,
    const float* lnzg, const float* lnzb,
    float* __restrict__ xl, float* __restrict__ yl, float* __restrict__ zl) {
  __shared__ float xs[64], ys[64];
  int row = blockIdx.x;            // b*N + n
  int c = threadIdx.x;
  int b = row / N_, n = row % N_;
  float xv = x[(size_t)(b * C_ + c) * N_ + n];
  float yv = y[(size_t)(b * C_ + c) * N_ + n];
  xs[c] = xv; ys[c] = yv;
  __syncthreads();
  const float4* wr  = (const float4*)(pw + (size_t)c * 2 * C_);
  const float4* xs4 = (const float4*)xs;
  const float4* ys4 = (const float4*)ys;
  float acc = pb[c];
#pragma unroll
  for (int t = 0; t < 16; ++t) {
    float4 a = xs4[t], wv = wr[t];
    acc += a.x * wv.x + a.y * wv.y + a.z * wv.z + a.w * wv.w;
  }
#pragma unroll
  for (int t = 0; t < 16; ++t) {
    float4 a = ys4[t], wv = wr[16 + t];
    acc += a.x * wv.x + a.y * wv.y + a.z * wv.z + a.w * wv.w;
  }
  float s  = g[c] * rsqrtf(v[c] + EPS_);
  float sh = bb[c] - m[c] * s;
  float tx = xv * s + sh;
  xl[(size_t)row * C_ + c] = ln_val(tx, lnxg[c], lnxb[c]);
  float ty = yv * s + sh;
  yl[(size_t)row * C_ + c] = ln_val(ty, lnyg[c], lnyb[c]);
  float tz = acc * s + sh;
  zl[(size_t)row * C_ + c] = ln_val(tz, lnzg[c], lnzb[c]);
}

// ------------- fused qv (both branches) + k projection --------------------
//   qxb [bh][n][8]  (scale FS_ folded in), qyb [bh][n][8]
//   kbf [bh][n][8]
//   vt  [bh][16][N]  rows 0-7 = Vx dims, rows 8-15 = Vy dims (transposed)
__global__ void k_qvk(const float* __restrict__ lnb, const float* __restrict__ zl,
                      const float* __restrict__ qvw, const float* __restrict__ qvb,
                      const float* __restrict__ kw, const float* __restrict__ kb,
                      u16* __restrict__ qxb, u16* __restrict__ qyb,
                      u16* __restrict__ kbf, u16* __restrict__ vt) {
  int z = blockIdx.z;
  if (z < 2) {
    int idx = blockIdx.x * 256 + threadIdx.x;   // B*N*128
    int j = idx & 127;
    int row = idx >> 7;
    int b = row / N_, n = row % N_;
    const float4* ir = (const float4*)(lnb + z * S_ + (size_t)row * C_);
    const float4* wr = (const float4*)(qvw + (size_t)j * C_);
    float acc = qvb[j];
#pragma unroll
    for (int t = 0; t < 16; ++t) {
      float4 a = ir[t], wv = wr[t];
      acc += a.x * wv.x + a.y * wv.y + a.z * wv.z + a.w * wv.w;
    }
    int jj = j & 63;
    int h = jj >> 3, d = jj & 7;
    int bh = b * NH_ + h;
    if (j < C_) {   // q
      float val = (z == 0) ? acc * FS_ : acc;
      u16* dst = (z == 0) ? qxb : qyb;
      dst[((size_t)bh * N_ + n) * 8 + d] = f2bf(val);
    } else {        // v (transposed store)
      vt[((size_t)bh * 16 + z * 8 + d) * N_ + n] = f2bf(acc);
    }
  } else {
    if (blockIdx.x >= 1152) return;
    int idx = blockIdx.x * 256 + threadIdx.x;   // B*N*64
    int j = idx & 63;
    int row = idx >> 6;
    int b = row / N_, n = row % N_;
    const float4* ir = (const float4*)(zl + (size_t)row * C_);
    const float4* wr = (const float4*)(kw + (size_t)j * C_);
    float acc = kb[j];
#pragma unroll
    for (int t = 0; t < 16; ++t) {
      float4 a = ir[t], wv = wr[t];
      acc += a.x * wv.x + a.y * wv.y + a.z * wv.z + a.w * wv.w;
    }
    int h = j >> 3, d = j & 7;
    kbf[((size_t)(b * NH_ + h) * N_ + n) * 8 + d] = f2bf(acc);
  }
}

// ---------------- attention v8: MFMA flash, 16-q tile, dual-branch --------
__global__ __launch_bounds__(128, 5) void k_attn8(
    const u16* __restrict__ qx, const u16* __restrict__ qy,
    const u16* __restrict__ kk, const u16* __restrict__ vt,
    float* __restrict__ outx, float* __restrict__ outy) {
  __shared__ float sAcc[2][4][64];
  __shared__ float sL[2][16];
  int qt = blockIdx.x, bh = blockIdx.y;
  int tid = threadIdx.x;
  int lane = tid & 63;
  int wave = tid >> 6;
  int l15 = lane & 15;
  int q0 = qt * 16;

  F8 qxf, qyf;
  size_t qoff = ((size_t)bh * N_ + q0 + l15) * 8;
  qxf.u4 = *(const uint4*)(qx + qoff);
  qyf.u4 = *(const uint4*)(qy + qoff);
  if (lane >= 16) {
    qxf.u4 = make_uint4(0u, 0u, 0u, 0u);
    qyf.u4 = make_uint4(0u, 0u, 0u, 0u);
  }

  int key0 = wave * (N_ / 2);
  const uint4* kp = (const uint4*)(kk + (size_t)bh * N_ * 8) + key0 + l15;
  const uint4* vp = (const uint4*)(vt + ((size_t)bh * 16 + l15) * N_ + key0)
                    + (lane >> 4);
  int addr0 = (((lane >> 4) & 1) * 32 + l15) * 4;
  int addr1 = addr0 + 64;
  int thi = lane >> 5;

  f32x4 acc = {0.f, 0.f, 0.f, 0.f};
  const f32x4 z4 = {0.f, 0.f, 0.f, 0.f};
  float lsum = 0.f;

  F8 ka, kb2, vf;
  ka.u4 = kp[0]; kb2.u4 = kp[16]; vf.u4 = *vp;
  for (int c = 0; c < 36; ++c) {
    F8 kaC = ka, kbC = kb2, vfC = vf;
    kp += 32; vp += 4;
    ka.u4 = kp[0]; kb2.u4 = kp[16]; vf.u4 = *vp;   // prefetch next chunk

    f32x4 s1a = __builtin_amdgcn_mfma_f32_16x16x32_bf16(kaC.s, qxf.s, z4, 0, 0, 0);
    f32x4 s2a = __builtin_amdgcn_mfma_f32_16x16x32_bf16(kaC.s, qyf.s, z4, 0, 0, 0);
    f32x4 s1b = __builtin_amdgcn_mfma_f32_16x16x32_bf16(kbC.s, qxf.s, z4, 0, 0, 0);
    f32x4 s2b = __builtin_amdgcn_mfma_f32_16x16x32_bf16(kbC.s, qyf.s, z4, 0, 0, 0);

    float p00 = exp2f(s1a[0] * s2a[0]), p01 = exp2f(s1a[1] * s2a[1]);
    float p02 = exp2f(s1a[2] * s2a[2]), p03 = exp2f(s1a[3] * s2a[3]);
    float p10 = exp2f(s1b[0] * s2b[0]), p11 = exp2f(s1b[1] * s2b[1]);
    float p12 = exp2f(s1b[2] * s2b[2]), p13 = exp2f(s1b[3] * s2b[3]);
    lsum += ((p00 + p01) + (p02 + p03)) + ((p10 + p11) + (p12 + p13));

    unsigned int pk00, pk10, pk01, pk11;
    asm("v_cvt_pk_bf16_f32 %0, %1, %2" : "=v"(pk00) : "v"(p00), "v"(p01));
    asm("v_cvt_pk_bf16_f32 %0, %1, %2" : "=v"(pk10) : "v"(p02), "v"(p03));
    asm("v_cvt_pk_bf16_f32 %0, %1, %2" : "=v"(pk01) : "v"(p10), "v"(p11));
    asm("v_cvt_pk_bf16_f32 %0, %1, %2" : "=v"(pk11) : "v"(p12), "v"(p13));

    int b00 = __builtin_amdgcn_ds_bpermute(addr0, (int)pk00);
    int b01 = __builtin_amdgcn_ds_bpermute(addr0, (int)pk01);
    int b10 = __builtin_amdgcn_ds_bpermute(addr0, (int)pk10);
    int b11 = __builtin_amdgcn_ds_bpermute(addr0, (int)pk11);
    int c00 = __builtin_amdgcn_ds_bpermute(addr1, (int)pk00);
    int c01 = __builtin_amdgcn_ds_bpermute(addr1, (int)pk01);
    int c10 = __builtin_amdgcn_ds_bpermute(addr1, (int)pk10);
    int c11 = __builtin_amdgcn_ds_bpermute(addr1, (int)pk11);

    F8 pf;
    pf.w[0] = (unsigned int)(thi ? b01 : b00);
    pf.w[1] = (unsigned int)(thi ? b11 : b10);
    pf.w[2] = (unsigned int)(thi ? c01 : c00);
    pf.w[3] = (unsigned int)(thi ? c11 : c10);
    acc = __builtin_amdgcn_mfma_f32_16x16x32_bf16(pf.s, vfC.s, acc, 0, 0, 0);
  }

  lsum += __shfl_xor(lsum, 16, 64);
  lsum += __shfl_xor(lsum, 32, 64);
  if (lane < 16) sL[wave][lane] = lsum;
#pragma unroll
  for (int r = 0; r < 4; ++r) sAcc[wave][r][lane] = acc[r];
  __syncthreads();
  if (wave == 0) {
    float Linv = 1.f / (sL[0][l15] + sL[1][l15]);
    int b = bh >> 3, h = bh & 7;
    int d = l15 & 7;
    float* ob = (l15 < 8) ? outx : outy;
    size_t cbase = (size_t)b * N_ * C_ + (size_t)h * 8 + d;
#pragma unroll
    for (int r = 0; r < 4; ++r) {
      int qrow = 4 * (lane >> 4) + r;
      float li = __shfl(Linv, qrow, 64);
      float a = sAcc[0][r][lane] + sAcc[1][r][lane];
      ob[cbase + (size_t)(q0 + qrow) * C_] = a * li;
    }
  }
}

// -------- proj v2: 2 couts + 2 px per thread (att rows shared) ------------
__global__ __launch_bounds__(64) void k_proj2(
    const float* __restrict__ attbase,
    const float* __restrict__ x, const float* __restrict__ y,
    const float* bg, const float* bb2, const float* bm, const float* bv,
    const float* __restrict__ pw, const float* __restrict__ pbias,
    float* __restrict__ outbase) {
  int p = blockIdx.x * 128 + threadIdx.x * 2;
  int c0 = blockIdx.y * 2;
  int z = blockIdx.z;
  int branch = z >> 1, b = z & 1;
  const float* att = attbase + branch * S_ + (size_t)b * N_ * C_;
  const float4* w0 = (const float4*)(pw + (size_t)c0 * C_);
  const float4* w1 = (const float4*)(pw + (size_t)(c0 + 1) * C_);
  const float4* ar0 = (const float4*)(att + (size_t)p * C_);
  const float4* ar1 = (const float4*)(att + (size_t)(p + 1) * C_);
  float bias0 = pbias[c0], bias1 = pbias[c0 + 1];
  float a00 = bias0, a01 = bias0, a10 = bias1, a11 = bias1;
#pragma unroll
  for (int t = 0; t < 16; ++t) {
    float4 v0 = ar0[t], v1 = ar1[t];
    float4 u = w0[t], w = w1[t];
    a00 += v0.x*u.x + v0.y*u.y + v0.z*u.z + v0.w*u.w;
    a01 += v1.x*u.x + v1.y*u.y + v1.z*u.z + v1.w*u.w;
    a10 += v0.x*w.x + v0.y*w.y + v0.z*w.z + v0.w*w.w;
    a11 += v1.x*w.x + v1.y*w.y + v1.z*w.z + v1.w*w.w;
  }
  float s0  = bg[c0] * rsqrtf(bv[c0] + EPS_);
  float sh0 = bb2[c0] - bm[c0] * s0;
  float s1  = bg[c0+1] * rsqrtf(bv[c0+1] + EPS_);
  float sh1 = bb2[c0+1] - bm[c0+1] * s1;
  const float* xin = branch ? y : x;
  float2 r0 = *(const float2*)(xin + ((size_t)b * C_ + c0) * N_ + p);
  float2 r1 = *(const float2*)(xin + ((size_t)b * C_ + c0 + 1) * N_ + p);
  size_t o = (size_t)z * CN_ + (size_t)c0 * N_ + p;
  *(float2*)(outbase + o)      = make_float2(a00 + r0.x * s0 + sh0,
                                             a01 + r0.y * s0 + sh0);
  *(float2*)(outbase + o + N_) = make_float2(a10 + r1.x * s1 + sh1,
                                             a11 + r1.y * s1 + sh1);
}

// ===== conv core v3: async LDS input staging (dbuf) + scalar weights ======
// Block = 1 wave, 256 px tile (4 px/thread), 2 couts. Per ci the 8-row
// input strip (48 cols, zero-filled halo rows) is staged into LDS for
// ci+1 while computing ci. Weights read via uniform global loads (s_load,
// scalar pipe), double-buffered in registers.
template<int CIN, int CIPB>
__device__ __forceinline__ void conv_core3(
    const float* __restrict__ ib, const float* __restrict__ w,
    int c0, int ci0, int p0, int tid, float (*bufs)[384],
    float4& A0, float4& A1) {
  const float* w0r = w + ((size_t)c0 * CIN + ci0) * 9;
  const float* w1r = w0r + (size_t)CIN * 9;
  int p  = p0 + tid * 4;
  int yy0 = p0 / W_;
  int yy = p / W_, x0 = p - yy * W_;
  int lr = yy - yy0;                     // 0..5 ; +ky in 0..7
  bool okL = x0 > 0, okR = x0 + 4 < W_;

  // staging geometry: 96 float4 chunks = 8 rows x 12; thread t does chunk
  // t, and chunk 64+t for t<32. Rows outside [0,H) -> zeros.
  int rf0 = tid / 12, cf0 = tid - rf0 * 12;
  int gy0 = yy0 - 1 + rf0;
  int rf1 = (64 + tid) / 12, cf1 = (64 + tid) - rf1 * 12;
  int gy1 = yy0 - 1 + rf1;
  bool v0 = (unsigned)gy0 < (unsigned)H_;
  bool v1 = (tid < 32) && ((unsigned)gy1 < (unsigned)H_);
  int o0 = gy0 * W_ + cf0 * 4;
  int o1 = gy1 * W_ + cf1 * 4;
  const float4 zz = make_float4(0.f, 0.f, 0.f, 0.f);

  // prologue: stage ci=0 into buf0, load weights for ci=0
  {
    const float* s = ib + (size_t)ci0 * N_;
    float4 ga = v0 ? *(const float4*)(s + o0) : zz;
    ((float4*)bufs[0])[tid] = ga;
    if (tid < 32) {
      float4 gb = v1 ? *(const float4*)(s + o1) : zz;
      ((float4*)bufs[0])[64 + tid] = gb;
    }
  }
  float wc[18];
#pragma unroll
  for (int i = 0; i < 9; ++i) { wc[i] = w0r[i]; wc[9 + i] = w1r[i]; }

#pragma unroll 2
  for (int ci = 0; ci < CIPB; ++ci) {
    float4 ga = zz, gb = zz;
    float wn[18];
    if (ci + 1 < CIPB) {
      const float* s = ib + (size_t)(ci0 + ci + 1) * N_;
      ga = v0 ? *(const float4*)(s + o0) : zz;
      gb = v1 ? *(const float4*)(s + o1) : zz;
      const float* nw0 = w0r + (ci + 1) * 9;
      const float* nw1 = w1r + (ci + 1) * 9;
#pragma unroll
      for (int i = 0; i < 9; ++i) { wn[i] = nw0[i]; wn[9 + i] = nw1[i]; }
    }
    const float* bc = bufs[ci & 1];
#pragma unroll
    for (int ky = 0; ky < 3; ++ky) {
      int base = (lr + ky) * W_ + x0;
      float4 mid = *(const float4*)(bc + base);
      float l = okL ? bc[base - 1] : 0.f;
      float r = okR ? bc[base + 4] : 0.f;
      float u0 = wc[ky*3], u1 = wc[ky*3+1], u2 = wc[ky*3+2];
      float t0 = wc[9+ky*3], t1 = wc[9+ky*3+1], t2 = wc[9+ky*3+2];
      A0.x += l     * u0 + mid.x * u1 + mid.y * u2;
      A0.y += mid.x * u0 + mid.y * u1 + mid.z * u2;
      A0.z += mid.y * u0 + mid.z * u1 + mid.w * u2;
      A0.w += mid.z * u0 + mid.w * u1 + r     * u2;
      A1.x += l     * t0 + mid.x * t1 + mid.y * t2;
      A1.y += mid.x * t0 + mid.y * t1 + mid.z * t2;
      A1.z += mid.y * t0 + mid.z * t1 + mid.w * t2;
      A1.w += mid.z * t0 + mid.w * t1 + r     * t2;
    }
    if (ci + 1 < CIPB) {
      float4* d = (float4*)bufs[(ci + 1) & 1];
      d[tid] = ga;
      if (tid < 32) d[64 + tid] = gb;
#pragma unroll
      for (int i = 0; i < 18; ++i) wc[i] = wn[i];
    }
  }
}

// ------ 64-cin conv RAW partial: cin half, 2 couts + 4 px -----------------
// grid (9, C_/2, 8), block 64. z: img = z&3 (layout img*CN), half = z>>2.
__global__ __launch_bounds__(64) void k_convs(
    const float* __restrict__ inA, const float* __restrict__ inB,
    const float* __restrict__ w,
    float* __restrict__ pA, float* __restrict__ pB) {
  __shared__ float bufs[2][384];
  int p0 = blockIdx.x * 256;
  int p = p0 + threadIdx.x * 4;
  int c0 = blockIdx.y * 2;
  int z = blockIdx.z;
  int img = z & 3, half = z >> 2;
  const float* ib = (img < 2) ? inA + (size_t)img * CN_
                              : inB + (size_t)(img - 2) * CN_;
  float4 A0 = make_float4(0.f,0.f,0.f,0.f);
  float4 A1 = make_float4(0.f,0.f,0.f,0.f);
  conv_core3<C_, C_/2>(ib, w, c0, half * (C_/2), p0, threadIdx.x, bufs, A0, A1);
  float* ob = (half ? pB : pA) + (size_t)img * CN_ + (size_t)c0 * N_ + p;
  *(float4*)(ob)      = A0;
  *(float4*)(ob + N_) = A1;
}

// ------ combine halves + bias + bn + relu (conv1 epilogue) ----------------
__global__ void k_combp(const float* __restrict__ pA, const float* __restrict__ pB,
                        const float* __restrict__ cb,
                        const float* __restrict__ g, const float* __restrict__ b2,
                        const float* __restrict__ m, const float* __restrict__ v,
                        float* __restrict__ tA, float* __restrict__ tB) {
  int t = blockIdx.x * 256 + threadIdx.x;
  int p4 = t * 4;
  int n = p4 % N_;
  int c = (p4 / N_) % C_;
  int img = p4 / (int)CN_;
  size_t off = (size_t)img * CN_ + (size_t)c * N_ + n;
  float4 a = *(const float4*)(pA + off);
  float4 d = *(const float4*)(pB + off);
  float s  = g[c] * rsqrtf(v[c] + EPS_);
  float sh = b2[c] - m[c] * s;
  float bias = cb[c];
  float4 r;
  r.x = fmaxf((a.x + d.x + bias) * s + sh, 0.f);
  r.y = fmaxf((a.y + d.y + bias) * s + sh, 0.f);
  r.z = fmaxf((a.z + d.z + bias) * s + sh, 0.f);
  r.w = fmaxf((a.w + d.w + bias) * s + sh, 0.f);
  float* ob = (img < 2) ? tA + off : tB + off - 2 * CN_;
  *(float4*)ob = r;
}

// ------ combine halves + bias + bn + relu + resid (conv2 epilogue) --------
__global__ void k_comb2(float* __restrict__ pA, const float* __restrict__ pB,
                        const float* __restrict__ cb,
                        const float* __restrict__ g, const float* __restrict__ b2,
                        const float* __restrict__ m, const float* __restrict__ v,
                        const float* __restrict__ resid) {
  int t = blockIdx.x * 256 + threadIdx.x;
  int p4 = t * 4;
  int n = p4 % N_;
  int c = (p4 / N_) % C_;
  int img = p4 / (int)CN_;
  size_t off = (size_t)img * CN_ + (size_t)c * N_ + n;
  float4 a = *(const float4*)(pA + off);
  float4 d = *(const float4*)(pB + off);
  float4 rr = *(const float4*)(resid + off);
  float s  = g[c] * rsqrtf(v[c] + EPS_);
  float sh = b2[c] - m[c] * s;
  float bias = cb[c];
  float4 r;
  r.x = fmaxf((a.x + d.x + bias) * s + sh, 0.f) + rr.x;
  r.y = fmaxf((a.y + d.y + bias) * s + sh, 0.f) + rr.y;
  r.z = fmaxf((a.z + d.z + bias) * s + sh, 0.f) + rr.z;
  r.w = fmaxf((a.w + d.w + bias) * s + sh, 0.f) + rr.w;
  *(float4*)(pA + off) = r;
}

// ------ cat = [xo+yo ; xo*yo] + bn2 -> fin, float4 ------------------------
__global__ void k_catbn(const float* __restrict__ o2,
                        const float* __restrict__ g, const float* __restrict__ b2,
                        const float* __restrict__ m, const float* __restrict__ v,
                        float* __restrict__ cat, float* __restrict__ fin,
                        size_t finStride) {
  int t = blockIdx.x * 256 + threadIdx.x;
  int p4 = t * 4;
  int n  = p4 % N_;
  int c2 = (p4 / N_) % (2 * C_);
  int b  = p4 / (2 * C_ * N_);
  int c  = c2 & 63;
  float4 X = *(const float4*)(o2 + (size_t)b * CN_ + (size_t)c * N_ + n);
  float4 Y = *(const float4*)(o2 + (size_t)(2 + b) * CN_ + (size_t)c * N_ + n);
  float4 val;
  if (c2 < C_) val = make_float4(X.x + Y.x, X.y + Y.y, X.z + Y.z, X.w + Y.w);
  else         val = make_float4(X.x * Y.x, X.y * Y.y, X.z * Y.z, X.w * Y.w);
  size_t co = ((size_t)b * 2 * C_ + c2) * N_ + n;
  *(float4*)(cat + co) = val;
  float s  = g[c2] * rsqrtf(v[c2] + EPS_);
  float sh = b2[c2] - m[c2] * s;
  *(float4*)(fin + (size_t)b * finStride + (size_t)c2 * N_ + n) =
      make_float4(val.x * s + sh, val.y * s + sh, val.z * s + sh, val.w * s + sh);
}

// ------ f-branch 3x3 conv partial (64-cin half), 2 couts + 4 px -----------
// grid (9, C_, 2*B_), block 64. z: b = z&1, half = z>>1.
__global__ __launch_bounds__(64) void k_fconvs(
    const float* __restrict__ in, size_t inStride,
    const float* __restrict__ w,
    float* __restrict__ outA, size_t outStrideA,
    float* __restrict__ outB, size_t outStrideB) {
  __shared__ float bufs[2][384];
  int p0 = blockIdx.x * 256;
  int p = p0 + threadIdx.x * 4;
  int c0 = blockIdx.y * 2;
  int z = blockIdx.z;
  int b = z & 1, half = z >> 1;
  const float* ib = in + (size_t)b * inStride;
  float4 A0 = make_float4(0.f,0.f,0.f,0.f);
  float4 A1 = make_float4(0.f,0.f,0.f,0.f);
  conv_core3<2*C_, C_>(ib, w, c0, half * C_, p0, threadIdx.x, bufs, A0, A1);
  float* ob = (half ? outB + (size_t)b * outStrideB
                    : outA + (size_t)b * outStrideA)
              + (size_t)c0 * N_ + p;
  *(float4*)(ob)      = A0;
  *(float4*)(ob + N_) = A1;
}

// ------ combine halves + bn + relu, float4 (in-place into A ok) -----------
__global__ void k_comb(const float* __restrict__ pA, size_t strideA,
                       const float* __restrict__ pB, size_t strideB,
                       const float* __restrict__ g, const float* __restrict__ b2,
                       const float* __restrict__ m, const float* __restrict__ v,
                       float* __restrict__ out, size_t outStride) {
  int t = blockIdx.x * 256 + threadIdx.x;
  int p4 = t * 4;
  int n = p4 % N_;
  int c = (p4 / N_) % (2 * C_);
  int b = p4 / (2 * C_ * N_);
  size_t off = (size_t)c * N_ + n;
  float4 a = *(const float4*)(pA + (size_t)b * strideA + off);
  float4 d = *(const float4*)(pB + (size_t)b * strideB + off);
  float s  = g[c] * rsqrtf(v[c] + EPS_);
  float sh = b2[c] - m[c] * s;
  float4 r;
  r.x = fmaxf((a.x + d.x) * s + sh, 0.f);
  r.y = fmaxf((a.y + d.y) * s + sh, 0.f);
  r.z = fmaxf((a.z + d.z) * s + sh, 0.f);
  r.w = fmaxf((a.w + d.w) * s + sh, 0.f);
  *(float4*)(out + (size_t)b * outStride + off) = r;
}

// -------- final v2: 2 couts/block, fused comb(fbn2)+relu + cat add --------
__global__ __launch_bounds__(64) void k_final3(
    const float* __restrict__ pA, size_t strideA,
    const float* __restrict__ pB, size_t strideB,
    const float* __restrict__ g2, const float* __restrict__ b2,
    const float* __restrict__ m2, const float* __restrict__ v2,
    const float* __restrict__ cat,
    const float* __restrict__ w, const float* __restrict__ fb,
    float* __restrict__ out) {
  __shared__ float fsc[2 * C_], fsh[2 * C_];
  for (int j = threadIdx.x; j < 2 * C_; j += 64) {
    float s = g2[j] * rsqrtf(v2[j] + EPS_);
    fsc[j] = s;
    fsh[j] = b2[j] - m2[j] * s;
  }
  __syncthreads();
  int p = blockIdx.x * 128 + threadIdx.x * 2;
  int c0 = blockIdx.y * 2;
  int b = blockIdx.z;
  const float* frA = pA + (size_t)b * strideA;
  const float* frB = pB + (size_t)b * strideB;
  const float* wr0 = w + (size_t)c0 * 2 * C_;
  const float* wr1 = wr0 + 2 * C_;
  float a00 = fb[c0], a01 = a00;
  float a10 = fb[c0 + 1], a11 = a10;
#pragma unroll 4
  for (int j = 0; j < 2 * C_; ++j) {
    float2 fa = *(const float2*)(frA + (size_t)j * N_ + p);
    float2 fd = *(const float2*)(frB + (size_t)j * N_ + p);
    float s = fsc[j], sh = fsh[j];
    float f0 = fmaxf((fa.x + fd.x) * s + sh, 0.f);
    float f1 = fmaxf((fa.y + fd.y) * s + sh, 0.f);
    float wv0 = wr0[j], wv1 = wr1[j];
    a00 += wv0 * f0; a01 += wv0 * f1;
    a10 += wv1 * f0; a11 += wv1 * f1;
  }
  size_t o = ((size_t)b * 2 * C_ + c0) * N_ + p;
  float2 cv0 = *(const float2*)(cat + o);
  float2 cv1 = *(const float2*)(cat + o + N_);
  *(float2*)(out + o)      = make_float2(a00 + cv0.x, a01 + cv0.y);
  *(float2*)(out + o + N_) = make_float2(a10 + cv1.x, a11 + cv1.y);
}

extern "C" void kernel_launch(void* const* d_in, const int* in_sizes, int n_in,
                              void* d_out, int out_size, void* d_ws, size_t ws_size,
                              hipStream_t stream) {
  const float* x       = (const float*)d_in[0];
  const float* y       = (const float*)d_in[1];
  const float* pconv_w = (const float*)d_in[2];
  const float* pconv_b = (const float*)d_in[3];
  const float* bnd_g = (const float*)d_in[4];
  const float* bnd_b = (const float*)d_in[5];
  const float* bnd_m = (const float*)d_in[6];
  const float* bnd_v = (const float*)d_in[7];
  const float* lnx_g = (const float*)d_in[8];
  const float* lnx_b = (const float*)d_in[9];
  const float* lny_g = (const float*)d_in[10];
  const float* lny_b = (const float*)d_in[11];
  const float* lnz_g = (const float*)d_in[12];
  const float* lnz_b = (const float*)d_in[13];
  const float* k_w   = (const float*)d_in[14];
  const float* k_b   = (const float*)d_in[15];
  const float* qv_w  = (const float*)d_in[16];
  const float* qv_b  = (const float*)d_in[17];
  const float* proj_w = (const float*)d_in[18];
  const float* proj_b = (const float*)d_in[19];
  const float* c2w1  = (const float*)d_in[20];
  const float* c2b1  = (const float*)d_in[21];
  const float* c2bn1_g = (const float*)d_in[22];
  const float* c2bn1_b = (const float*)d_in[23];
  const float* c2bn1_m = (const float*)d_in[24];
  const float* c2bn1_v = (const float*)d_in[25];
  const float* c2w2  = (const float*)d_in[26];
  const float* c2b2  = (const float*)d_in[27];
  const float* c2bn2_g = (const float*)d_in[28];
  const float* c2bn2_b = (const float*)d_in[29];
  const float* c2bn2_m = (const float*)d_in[30];
  const float* c2bn2_v = (const float*)d_in[31];
  const float* bn2_g = (const float*)d_in[32];
  const float* bn2_b = (const float*)d_in[33];
  const float* bn2_m = (const float*)d_in[34];
  const float* bn2_v = (const float*)d_in[35];
  const float* f1w   = (const float*)d_in[36];
  const float* fbn1_g = (const float*)d_in[37];
  const float* fbn1_b = (const float*)d_in[38];
  const float* fbn1_m = (const float*)d_in[39];
  const float* fbn1_v = (const float*)d_in[40];
  const float* f2w   = (const float*)d_in[41];
  const float* fbn2_g = (const float*)d_in[42];
  const float* fbn2_b = (const float*)d_in[43];
  const float* fbn2_m = (const float*)d_in[44];
  const float* fbn2_v = (const float*)d_in[45];
  const float* f3w   = (const float*)d_in[46];
  const float* f3b   = (const float*)d_in[47];

  float* ws = (float*)d_ws;
  float* sl0 = ws + 0 * S_;
  float* sl1 = ws + 1 * S_;
  float* sl2 = ws + 2 * S_;
  float* sl3 = ws + 3 * S_;
  float* sl4 = ws + 4 * S_;
  float* sl5 = ws + 5 * S_;
  float* sl7 = ws + 7 * S_;

  // A. fused pconv + bn + ln
  k_pre<<<B_ * N_, 64, 0, stream>>>(x, y, pconv_w, pconv_b,
                                    bnd_g, bnd_b, bnd_m, bnd_v,
                                    lnx_g, lnx_b, lny_g, lny_b, lnz_g, lnz_b,
                                    sl1, sl2, sl3);
  // B. fused qv + kproj -> bf16 attention operands
  u16* qxb = (u16*)sl4;
  u16* qyb = qxb + (size_t)B_ * NH_ * N_ * 8;
  u16* kbf = (u16*)sl5;
  u16* vtb = (u16*)(ws + 6 * S_);
  {
    dim3 g(2304, 1, 3);
    k_qvk<<<g, 256, 0, stream>>>(sl1, sl3, qv_w, qv_b, k_w, k_b,
                                 qxb, qyb, kbf, vtb);
  }
  // C. attention v8 (MFMA) -> att_xo(1), att_yo(2)
  {
    dim3 g(N_ / 16, B_ * NH_);
    k_attn8<<<g, 128, 0, stream>>>(qxb, qyb, kbf, vtb, sl1, sl2);
  }
  // D. proj v2 (2 couts) -> xo4(3,4)
  {
    dim3 g(18, C_ / 2, 2 * B_);
    k_proj2<<<g, 64, 0, stream>>>(sl1, x, y, bnd_g, bnd_b, bnd_m, bnd_v,
                                  proj_w, proj_b, sl3);
  }
  // E. conv1: cin-split raw partials (4 px) + combine epilogue -> tmp(0 / 7)
  {
    dim3 g(9, C_ / 2, 8);
    k_convs<<<g, 64, 0, stream>>>(sl3, sl3 + 2 * CN_, c2w1, sl1, sl5);
    k_combp<<<576, 256, 0, stream>>>(sl1, sl5, c2b1,
        c2bn1_g, c2bn1_b, c2bn1_m, c2bn1_v, sl0, sl7);
  }
  // F. conv2: cin-split raw partials (4 px) + combine(+resid) -> o2(1,2)
  {
    dim3 g(9, C_ / 2, 8);
    k_convs<<<g, 64, 0, stream>>>(sl0, sl7, c2w2, sl1, sl5);
    k_comb2<<<576, 256, 0, stream>>>(sl1, sl5, c2b2,
        c2bn2_g, c2bn2_b, c2bn2_m, c2bn2_v, sl3);
  }
  // G. cat + bn2 -> cat(3,4), fin(0 / 7)
  k_catbn<<<576, 256, 0, stream>>>(sl1, bn2_g, bn2_b, bn2_m, bn2_v,
                                   sl3, sl0, 7 * S_);
  // H. f-branch convs, ci-split, 4 px/thread
  {
    dim3 g(9, C_, 2 * B_);
    k_fconvs<<<g, 64, 0, stream>>>(sl0, 7 * S_, f1w, sl1, S_, sl5, S_);
    k_comb<<<576, 256, 0, stream>>>(sl1, S_, sl5, S_,
                                    fbn1_g, fbn1_b, fbn1_m, fbn1_v, sl1, S_);
    k_fconvs<<<g, 64, 0, stream>>>(sl1, S_, f2w, sl5, S_, sl0, 7 * S_);
  }
  // I. final v2 (2 couts) -> fp32 out
  {
    dim3 g(18, C_, B_);
    k_final3<<<g, 64, 0, stream>>>(sl5, S_, sl0, 7 * S_,
                                   fbn2_g, fbn2_b, fbn2_m, fbn2_v,
                                   sl3, f3w, f3b, (float*)d_out);
  }
}

// Round 5
// 409.645 us; speedup vs baseline: 1.4786x; 1.0981x over previous
//
#include <hip/hip_runtime.h>
#include <hip/hip_bf16.h>

#define B_   2
#define C_   64
#define H_   48
#define W_   48
#define N_   (H_*W_)     // 2304
#define NH_  8
#define HD_  8
#define EPS_ 1e-5f
#define S2_  0.125f      // scale^2 = 1/hd
#define LOG2E_ 1.44269504f
#define FS_  (S2_ * LOG2E_)
#define S_   ((size_t)B_ * C_ * N_)   // 294912 floats per workspace slot
#define CN_  ((size_t)C_ * N_)        // 147456 floats per image

typedef unsigned short u16;
typedef __attribute__((ext_vector_type(8))) short short8v;
typedef __attribute__((ext_vector_type(4))) float f32x4;
union F8 { uint4 u4; short8v s; unsigned int w[4]; };

__device__ __forceinline__ float wsum64(float v) {
#pragma unroll
  for (int o = 32; o > 0; o >>= 1) v += __shfl_xor(v, o, 64);
  return v;
}

__device__ __forceinline__ float ln_val(float t, float g, float b) {
  float mu  = wsum64(t) * (1.0f / 64.0f);
  float d   = t - mu;
  float var = wsum64(d * d) * (1.0f / 64.0f);
  return d * rsqrtf(var + EPS_) * g + b;
}

// round-to-nearest-even f32 -> bf16 (finite inputs only)
__device__ __forceinline__ u16 f2bf(float x) {
  union { float f; unsigned int u; } a; a.f = x;
  unsigned int r = a.u + 0x7fffu + ((a.u >> 16) & 1u);
  return (u16)(r >> 16);
}

// ---- fused 1x1 pconv + BN + 3x LayerNorm; v2: 16 rows/block, LDS pw^T ----
// grid 288, block 1024 (16 waves, wave = one (b,n) row).
__global__ __launch_bounds__(1024) void k_pre(
    const float* __restrict__ x, const float* __restrict__ y,
    const float* __restrict__ pw, const float* __restrict__ pb,
    const float* g, const float* bb, const float* m, const float* v,
    const float* lnxg, const float* lnxb,
    const float* lnyg, const float* lnyb,
    const float* lnzg, const float* lnzb,
    float* __restrict__ xl, float* __restrict__ yl, float* __restrict__ zl) {
  __shared__ float4 pwT[32][64];           // pwT[i4][c] = pw[c][4*i4..+3]
  __shared__ float xs[16][64], ys[16][64];
  int w = threadIdx.x >> 6, c = threadIdx.x & 63;
  // stage pw transposed (strided global read, conflict-free LDS write)
  for (int idx = threadIdx.x; idx < 2048; idx += 1024) {
    int cc = idx & 63, i4 = idx >> 6;
    pwT[i4][cc] = *(const float4*)(pw + (size_t)cc * 2 * C_ + i4 * 4);
  }
  int row = blockIdx.x * 16 + w;           // b*N + n
  int b = row / N_, n = row % N_;
  float xv = x[(size_t)(b * C_ + c) * N_ + n];
  float yv = y[(size_t)(b * C_ + c) * N_ + n];
  xs[w][c] = xv; ys[w][c] = yv;
  __syncthreads();
  const float4* xw = (const float4*)xs[w];
  const float4* yw = (const float4*)ys[w];
  float acc = pb[c];
#pragma unroll
  for (int t = 0; t < 16; ++t) {
    float4 a = xw[t], wv = pwT[t][c];
    acc += a.x * wv.x + a.y * wv.y + a.z * wv.z + a.w * wv.w;
  }
#pragma unroll
  for (int t = 0; t < 16; ++t) {
    float4 a = yw[t], wv = pwT[16 + t][c];
    acc += a.x * wv.x + a.y * wv.y + a.z * wv.z + a.w * wv.w;
  }
  float s  = g[c] * rsqrtf(v[c] + EPS_);
  float sh = bb[c] - m[c] * s;
  float tx = xv * s + sh;
  xl[(size_t)row * C_ + c] = ln_val(tx, lnxg[c], lnxb[c]);
  float ty = yv * s + sh;
  yl[(size_t)row * C_ + c] = ln_val(ty, lnyg[c], lnyb[c]);
  float tz = acc * s + sh;
  zl[(size_t)row * C_ + c] = ln_val(tz, lnzg[c], lnzb[c]);
}

// ------------- qv/k projection v2: lane = row, uniform weights ------------
// grid (72, 20), block 64. blockIdx.y: part = y/4 (0 xq,1 xv,2 yq,3 yv,4 k),
// quarter = y&3 -> j0 = quarter*16. Weight reads are wave-uniform (scalar
// pipe); input row held in registers; outputs coalesced over n.
//   qxb [bh][n][8] (FS_ folded), qyb [bh][n][8], kbf [bh][n][8]
//   vt  [bh][16][N] rows 0-7 = Vx dims, 8-15 = Vy dims
__global__ __launch_bounds__(64) void k_qvk(
    const float* __restrict__ xl, const float* __restrict__ yl,
    const float* __restrict__ zl,
    const float* __restrict__ qvw, const float* __restrict__ qvb,
    const float* __restrict__ kw, const float* __restrict__ kb,
    u16* __restrict__ qxb, u16* __restrict__ qyb,
    u16* __restrict__ kbf, u16* __restrict__ vt) {
  int l = threadIdx.x;
  int part = blockIdx.y >> 2;
  int j0 = (blockIdx.y & 3) * 16;
  int row = blockIdx.x * 64 + l;
  int b = row / N_, n = row % N_;
  const float* inp = (part < 2) ? xl : (part < 4) ? yl : zl;
  float4 in[16];
  const float4* ir = (const float4*)(inp + (size_t)row * C_);
#pragma unroll
  for (int t = 0; t < 16; ++t) in[t] = ir[t];

  const float* wb   = (part == 4) ? kw : qvw;
  const float* bias = (part == 4) ? kb : qvb;
  int joff = (part == 1 || part == 3) ? 64 : 0;

  if (part == 1 || part == 3) {
    int vbase = (part == 1) ? 0 : 8;
#pragma unroll
    for (int jj = 0; jj < 16; ++jj) {
      int j = j0 + jj;
      const float4* wr = (const float4*)(wb + (size_t)(joff + j) * C_);
      float acc = bias[joff + j];
#pragma unroll
      for (int t = 0; t < 16; ++t) {
        float4 a = in[t], wv = wr[t];
        acc += a.x * wv.x + a.y * wv.y + a.z * wv.z + a.w * wv.w;
      }
      int h = j >> 3, d = j & 7;
      vt[((size_t)((b * NH_ + h) * 16 + vbase + d)) * N_ + n] = f2bf(acc);
    }
  } else {
    u16* dst = (part == 0) ? qxb : (part == 2) ? qyb : kbf;
#pragma unroll
    for (int gg = 0; gg < 2; ++gg) {
      int h = (j0 >> 3) + gg;
      union { uint4 u4; u16 s[8]; } pk;
#pragma unroll
      for (int d = 0; d < 8; ++d) {
        int j = h * 8 + d;
        const float4* wr = (const float4*)(wb + (size_t)(joff + j) * C_);
        float acc = bias[joff + j];
#pragma unroll
        for (int t = 0; t < 16; ++t) {
          float4 a = in[t], wv = wr[t];
          acc += a.x * wv.x + a.y * wv.y + a.z * wv.z + a.w * wv.w;
        }
        if (part == 0) acc *= FS_;
        pk.s[d] = f2bf(acc);
      }
      *(uint4*)(dst + ((size_t)(b * NH_ + h) * N_ + n) * 8) = pk.u4;
    }
  }
}

// ---------------- attention v8: MFMA flash, 16-q tile, dual-branch --------
__global__ __launch_bounds__(128, 5) void k_attn8(
    const u16* __restrict__ qx, const u16* __restrict__ qy,
    const u16* __restrict__ kk, const u16* __restrict__ vt,
    float* __restrict__ outx, float* __restrict__ outy) {
  __shared__ float sAcc[2][4][64];
  __shared__ float sL[2][16];
  int qt = blockIdx.x, bh = blockIdx.y;
  int tid = threadIdx.x;
  int lane = tid & 63;
  int wave = tid >> 6;
  int l15 = lane & 15;
  int q0 = qt * 16;

  F8 qxf, qyf;
  size_t qoff = ((size_t)bh * N_ + q0 + l15) * 8;
  qxf.u4 = *(const uint4*)(qx + qoff);
  qyf.u4 = *(const uint4*)(qy + qoff);
  if (lane >= 16) {
    qxf.u4 = make_uint4(0u, 0u, 0u, 0u);
    qyf.u4 = make_uint4(0u, 0u, 0u, 0u);
  }

  int key0 = wave * (N_ / 2);
  const uint4* kp = (const uint4*)(kk + (size_t)bh * N_ * 8) + key0 + l15;
  const uint4* vp = (const uint4*)(vt + ((size_t)bh * 16 + l15) * N_ + key0)
                    + (lane >> 4);
  int addr0 = (((lane >> 4) & 1) * 32 + l15) * 4;
  int addr1 = addr0 + 64;
  int thi = lane >> 5;

  f32x4 acc = {0.f, 0.f, 0.f, 0.f};
  const f32x4 z4 = {0.f, 0.f, 0.f, 0.f};
  float lsum = 0.f;

  F8 ka, kb2, vf;
  ka.u4 = kp[0]; kb2.u4 = kp[16]; vf.u4 = *vp;
  for (int c = 0; c < 36; ++c) {
    F8 kaC = ka, kbC = kb2, vfC = vf;
    kp += 32; vp += 4;
    ka.u4 = kp[0]; kb2.u4 = kp[16]; vf.u4 = *vp;   // prefetch next chunk

    f32x4 s1a = __builtin_amdgcn_mfma_f32_16x16x32_bf16(kaC.s, qxf.s, z4, 0, 0, 0);
    f32x4 s2a = __builtin_amdgcn_mfma_f32_16x16x32_bf16(kaC.s, qyf.s, z4, 0, 0, 0);
    f32x4 s1b = __builtin_amdgcn_mfma_f32_16x16x32_bf16(kbC.s, qxf.s, z4, 0, 0, 0);
    f32x4 s2b = __builtin_amdgcn_mfma_f32_16x16x32_bf16(kbC.s, qyf.s, z4, 0, 0, 0);

    float p00 = exp2f(s1a[0] * s2a[0]), p01 = exp2f(s1a[1] * s2a[1]);
    float p02 = exp2f(s1a[2] * s2a[2]), p03 = exp2f(s1a[3] * s2a[3]);
    float p10 = exp2f(s1b[0] * s2b[0]), p11 = exp2f(s1b[1] * s2b[1]);
    float p12 = exp2f(s1b[2] * s2b[2]), p13 = exp2f(s1b[3] * s2b[3]);
    lsum += ((p00 + p01) + (p02 + p03)) + ((p10 + p11) + (p12 + p13));

    unsigned int pk00, pk10, pk01, pk11;
    asm("v_cvt_pk_bf16_f32 %0, %1, %2" : "=v"(pk00) : "v"(p00), "v"(p01));
    asm("v_cvt_pk_bf16_f32 %0, %1, %2" : "=v"(pk10) : "v"(p02), "v"(p03));
    asm("v_cvt_pk_bf16_f32 %0, %1, %2" : "=v"(pk01) : "v"(p10), "v"(p11));
    asm("v_cvt_pk_bf16_f32 %0, %1, %2" : "=v"(pk11) : "v"(p12), "v"(p13));

    int b00 = __builtin_amdgcn_ds_bpermute(addr0, (int)pk00);
    int b01 = __builtin_amdgcn_ds_bpermute(addr0, (int)pk01);
    int b10 = __builtin_amdgcn_ds_bpermute(addr0, (int)pk10);
    int b11 = __builtin_amdgcn_ds_bpermute(addr0, (int)pk11);
    int c00 = __builtin_amdgcn_ds_bpermute(addr1, (int)pk00);
    int c01 = __builtin_amdgcn_ds_bpermute(addr1, (int)pk01);
    int c10 = __builtin_amdgcn_ds_bpermute(addr1, (int)pk10);
    int c11 = __builtin_amdgcn_ds_bpermute(addr1, (int)pk11);

    F8 pf;
    pf.w[0] = (unsigned int)(thi ? b01 : b00);
    pf.w[1] = (unsigned int)(thi ? b11 : b10);
    pf.w[2] = (unsigned int)(thi ? c01 : c00);
    pf.w[3] = (unsigned int)(thi ? c11 : c10);
    acc = __builtin_amdgcn_mfma_f32_16x16x32_bf16(pf.s, vfC.s, acc, 0, 0, 0);
  }

  lsum += __shfl_xor(lsum, 16, 64);
  lsum += __shfl_xor(lsum, 32, 64);
  if (lane < 16) sL[wave][lane] = lsum;
#pragma unroll
  for (int r = 0; r < 4; ++r) sAcc[wave][r][lane] = acc[r];
  __syncthreads();
  if (wave == 0) {
    float Linv = 1.f / (sL[0][l15] + sL[1][l15]);
    int b = bh >> 3, h = bh & 7;
    int d = l15 & 7;
    float* ob = (l15 < 8) ? outx : outy;
    size_t cbase = (size_t)b * N_ * C_ + (size_t)h * 8 + d;
#pragma unroll
    for (int r = 0; r < 4; ++r) {
      int qrow = 4 * (lane >> 4) + r;
      float li = __shfl(Linv, qrow, 64);
      float a = sAcc[0][r][lane] + sAcc[1][r][lane];
      ob[cbase + (size_t)(q0 + qrow) * C_] = a * li;
    }
  }
}

// -------- proj v2: 2 couts + 2 px per thread (att rows shared) ------------
__global__ __launch_bounds__(64) void k_proj2(
    const float* __restrict__ attbase,
    const float* __restrict__ x, const float* __restrict__ y,
    const float* bg, const float* bb2, const float* bm, const float* bv,
    const float* __restrict__ pw, const float* __restrict__ pbias,
    float* __restrict__ outbase) {
  int p = blockIdx.x * 128 + threadIdx.x * 2;
  int c0 = blockIdx.y * 2;
  int z = blockIdx.z;
  int branch = z >> 1, b = z & 1;
  const float* att = attbase + branch * S_ + (size_t)b * N_ * C_;
  const float4* w0 = (const float4*)(pw + (size_t)c0 * C_);
  const float4* w1 = (const float4*)(pw + (size_t)(c0 + 1) * C_);
  const float4* ar0 = (const float4*)(att + (size_t)p * C_);
  const float4* ar1 = (const float4*)(att + (size_t)(p + 1) * C_);
  float bias0 = pbias[c0], bias1 = pbias[c0 + 1];
  float a00 = bias0, a01 = bias0, a10 = bias1, a11 = bias1;
#pragma unroll
  for (int t = 0; t < 16; ++t) {
    float4 v0 = ar0[t], v1 = ar1[t];
    float4 u = w0[t], w = w1[t];
    a00 += v0.x*u.x + v0.y*u.y + v0.z*u.z + v0.w*u.w;
    a01 += v1.x*u.x + v1.y*u.y + v1.z*u.z + v1.w*u.w;
    a10 += v0.x*w.x + v0.y*w.y + v0.z*w.z + v0.w*w.w;
    a11 += v1.x*w.x + v1.y*w.y + v1.z*w.z + v1.w*w.w;
  }
  float s0  = bg[c0] * rsqrtf(bv[c0] + EPS_);
  float sh0 = bb2[c0] - bm[c0] * s0;
  float s1  = bg[c0+1] * rsqrtf(bv[c0+1] + EPS_);
  float sh1 = bb2[c0+1] - bm[c0+1] * s1;
  const float* xin = branch ? y : x;
  float2 r0 = *(const float2*)(xin + ((size_t)b * C_ + c0) * N_ + p);
  float2 r1 = *(const float2*)(xin + ((size_t)b * C_ + c0 + 1) * N_ + p);
  size_t o = (size_t)z * CN_ + (size_t)c0 * N_ + p;
  *(float2*)(outbase + o)      = make_float2(a00 + r0.x * s0 + sh0,
                                             a01 + r0.y * s0 + sh0);
  *(float2*)(outbase + o + N_) = make_float2(a10 + r1.x * s1 + sh1,
                                             a11 + r1.y * s1 + sh1);
}

// ===== conv core v3: async LDS input staging (dbuf) + scalar weights ======
template<int CIN, int CIPB>
__device__ __forceinline__ void conv_core3(
    const float* __restrict__ ib, const float* __restrict__ w,
    int c0, int ci0, int p0, int tid, float (*bufs)[384],
    float4& A0, float4& A1) {
  const float* w0r = w + ((size_t)c0 * CIN + ci0) * 9;
  const float* w1r = w0r + (size_t)CIN * 9;
  int p  = p0 + tid * 4;
  int yy0 = p0 / W_;
  int yy = p / W_, x0 = p - yy * W_;
  int lr = yy - yy0;                     // 0..5 ; +ky in 0..7
  bool okL = x0 > 0, okR = x0 + 4 < W_;

  int rf0 = tid / 12, cf0 = tid - rf0 * 12;
  int gy0 = yy0 - 1 + rf0;
  int rf1 = (64 + tid) / 12, cf1 = (64 + tid) - rf1 * 12;
  int gy1 = yy0 - 1 + rf1;
  bool v0 = (unsigned)gy0 < (unsigned)H_;
  bool v1 = (tid < 32) && ((unsigned)gy1 < (unsigned)H_);
  int o0 = gy0 * W_ + cf0 * 4;
  int o1 = gy1 * W_ + cf1 * 4;
  const float4 zz = make_float4(0.f, 0.f, 0.f, 0.f);

  {
    const float* s = ib + (size_t)ci0 * N_;
    float4 ga = v0 ? *(const float4*)(s + o0) : zz;
    ((float4*)bufs[0])[tid] = ga;
    if (tid < 32) {
      float4 gb = v1 ? *(const float4*)(s + o1) : zz;
      ((float4*)bufs[0])[64 + tid] = gb;
    }
  }
  float wc[18];
#pragma unroll
  for (int i = 0; i < 9; ++i) { wc[i] = w0r[i]; wc[9 + i] = w1r[i]; }

#pragma unroll 2
  for (int ci = 0; ci < CIPB; ++ci) {
    float4 ga = zz, gb = zz;
    float wn[18];
    if (ci + 1 < CIPB) {
      const float* s = ib + (size_t)(ci0 + ci + 1) * N_;
      ga = v0 ? *(const float4*)(s + o0) : zz;
      gb = v1 ? *(const float4*)(s + o1) : zz;
      const float* nw0 = w0r + (ci + 1) * 9;
      const float* nw1 = w1r + (ci + 1) * 9;
#pragma unroll
      for (int i = 0; i < 9; ++i) { wn[i] = nw0[i]; wn[9 + i] = nw1[i]; }
    }
    const float* bc = bufs[ci & 1];
#pragma unroll
    for (int ky = 0; ky < 3; ++ky) {
      int base = (lr + ky) * W_ + x0;
      float4 mid = *(const float4*)(bc + base);
      float l = okL ? bc[base - 1] : 0.f;
      float r = okR ? bc[base + 4] : 0.f;
      float u0 = wc[ky*3], u1 = wc[ky*3+1], u2 = wc[ky*3+2];
      float t0 = wc[9+ky*3], t1 = wc[9+ky*3+1], t2 = wc[9+ky*3+2];
      A0.x += l     * u0 + mid.x * u1 + mid.y * u2;
      A0.y += mid.x * u0 + mid.y * u1 + mid.z * u2;
      A0.z += mid.y * u0 + mid.z * u1 + mid.w * u2;
      A0.w += mid.z * u0 + mid.w * u1 + r     * u2;
      A1.x += l     * t0 + mid.x * t1 + mid.y * t2;
      A1.y += mid.x * t0 + mid.y * t1 + mid.z * t2;
      A1.z += mid.y * t0 + mid.z * t1 + mid.w * t2;
      A1.w += mid.z * t0 + mid.w * t1 + r     * t2;
    }
    if (ci + 1 < CIPB) {
      float4* d = (float4*)bufs[(ci + 1) & 1];
      d[tid] = ga;
      if (tid < 32) d[64 + tid] = gb;
#pragma unroll
      for (int i = 0; i < 18; ++i) wc[i] = wn[i];
    }
  }
}

// ------ 64-cin conv RAW partial: cin half, 2 couts + 4 px -----------------
__global__ __launch_bounds__(64) void k_convs(
    const float* __restrict__ inA, const float* __restrict__ inB,
    const float* __restrict__ w,
    float* __restrict__ pA, float* __restrict__ pB) {
  __shared__ float bufs[2][384];
  int p0 = blockIdx.x * 256;
  int p = p0 + threadIdx.x * 4;
  int c0 = blockIdx.y * 2;
  int z = blockIdx.z;
  int img = z & 3, half = z >> 2;
  const float* ib = (img < 2) ? inA + (size_t)img * CN_
                              : inB + (size_t)(img - 2) * CN_;
  float4 A0 = make_float4(0.f,0.f,0.f,0.f);
  float4 A1 = make_float4(0.f,0.f,0.f,0.f);
  conv_core3<C_, C_/2>(ib, w, c0, half * (C_/2), p0, threadIdx.x, bufs, A0, A1);
  float* ob = (half ? pB : pA) + (size_t)img * CN_ + (size_t)c0 * N_ + p;
  *(float4*)(ob)      = A0;
  *(float4*)(ob + N_) = A1;
}

// ------ combine halves + bias + bn + relu (conv1 epilogue) ----------------
__global__ void k_combp(const float* __restrict__ pA, const float* __restrict__ pB,
                        const float* __restrict__ cb,
                        const float* __restrict__ g, const float* __restrict__ b2,
                        const float* __restrict__ m, const float* __restrict__ v,
                        float* __restrict__ tA, float* __restrict__ tB) {
  int t = blockIdx.x * 256 + threadIdx.x;
  int p4 = t * 4;
  int n = p4 % N_;
  int c = (p4 / N_) % C_;
  int img = p4 / (int)CN_;
  size_t off = (size_t)img * CN_ + (size_t)c * N_ + n;
  float4 a = *(const float4*)(pA + off);
  float4 d = *(const float4*)(pB + off);
  float s  = g[c] * rsqrtf(v[c] + EPS_);
  float sh = b2[c] - m[c] * s;
  float bias = cb[c];
  float4 r;
  r.x = fmaxf((a.x + d.x + bias) * s + sh, 0.f);
  r.y = fmaxf((a.y + d.y + bias) * s + sh, 0.f);
  r.z = fmaxf((a.z + d.z + bias) * s + sh, 0.f);
  r.w = fmaxf((a.w + d.w + bias) * s + sh, 0.f);
  float* ob = (img < 2) ? tA + off : tB + off - 2 * CN_;
  *(float4*)ob = r;
}

// ------ combine halves + bias + bn + relu + resid (conv2 epilogue) --------
__global__ void k_comb2(float* __restrict__ pA, const float* __restrict__ pB,
                        const float* __restrict__ cb,
                        const float* __restrict__ g, const float* __restrict__ b2,
                        const float* __restrict__ m, const float* __restrict__ v,
                        const float* __restrict__ resid) {
  int t = blockIdx.x * 256 + threadIdx.x;
  int p4 = t * 4;
  int n = p4 % N_;
  int c = (p4 / N_) % C_;
  int img = p4 / (int)CN_;
  size_t off = (size_t)img * CN_ + (size_t)c * N_ + n;
  float4 a = *(const float4*)(pA + off);
  float4 d = *(const float4*)(pB + off);
  float4 rr = *(const float4*)(resid + off);
  float s  = g[c] * rsqrtf(v[c] + EPS_);
  float sh = b2[c] - m[c] * s;
  float bias = cb[c];
  float4 r;
  r.x = fmaxf((a.x + d.x + bias) * s + sh, 0.f) + rr.x;
  r.y = fmaxf((a.y + d.y + bias) * s + sh, 0.f) + rr.y;
  r.z = fmaxf((a.z + d.z + bias) * s + sh, 0.f) + rr.z;
  r.w = fmaxf((a.w + d.w + bias) * s + sh, 0.f) + rr.w;
  *(float4*)(pA + off) = r;
}

// ------ cat = [xo+yo ; xo*yo] + bn2 -> fin, float4 ------------------------
__global__ void k_catbn(const float* __restrict__ o2,
                        const float* __restrict__ g, const float* __restrict__ b2,
                        const float* __restrict__ m, const float* __restrict__ v,
                        float* __restrict__ cat, float* __restrict__ fin,
                        size_t finStride) {
  int t = blockIdx.x * 256 + threadIdx.x;
  int p4 = t * 4;
  int n  = p4 % N_;
  int c2 = (p4 / N_) % (2 * C_);
  int b  = p4 / (2 * C_ * N_);
  int c  = c2 & 63;
  float4 X = *(const float4*)(o2 + (size_t)b * CN_ + (size_t)c * N_ + n);
  float4 Y = *(const float4*)(o2 + (size_t)(2 + b) * CN_ + (size_t)c * N_ + n);
  float4 val;
  if (c2 < C_) val = make_float4(X.x + Y.x, X.y + Y.y, X.z + Y.z, X.w + Y.w);
  else         val = make_float4(X.x * Y.x, X.y * Y.y, X.z * Y.z, X.w * Y.w);
  size_t co = ((size_t)b * 2 * C_ + c2) * N_ + n;
  *(float4*)(cat + co) = val;
  float s  = g[c2] * rsqrtf(v[c2] + EPS_);
  float sh = b2[c2] - m[c2] * s;
  *(float4*)(fin + (size_t)b * finStride + (size_t)c2 * N_ + n) =
      make_float4(val.x * s + sh, val.y * s + sh, val.z * s + sh, val.w * s + sh);
}

// ------ f-branch 3x3 conv partial (64-cin half), 2 couts + 4 px -----------
__global__ __launch_bounds__(64) void k_fconvs(
    const float* __restrict__ in, size_t inStride,
    const float* __restrict__ w,
    float* __restrict__ outA, size_t outStrideA,
    float* __restrict__ outB, size_t outStrideB) {
  __shared__ float bufs[2][384];
  int p0 = blockIdx.x * 256;
  int p = p0 + threadIdx.x * 4;
  int c0 = blockIdx.y * 2;
  int z = blockIdx.z;
  int b = z & 1, half = z >> 1;
  const float* ib = in + (size_t)b * inStride;
  float4 A0 = make_float4(0.f,0.f,0.f,0.f);
  float4 A1 = make_float4(0.f,0.f,0.f,0.f);
  conv_core3<2*C_, C_>(ib, w, c0, half * C_, p0, threadIdx.x, bufs, A0, A1);
  float* ob = (half ? outB + (size_t)b * outStrideB
                    : outA + (size_t)b * outStrideA)
              + (size_t)c0 * N_ + p;
  *(float4*)(ob)      = A0;
  *(float4*)(ob + N_) = A1;
}

// ------ combine halves + bn + relu, float4 (in-place into A ok) -----------
__global__ void k_comb(const float* __restrict__ pA, size_t strideA,
                       const float* __restrict__ pB, size_t strideB,
                       const float* __restrict__ g, const float* __restrict__ b2,
                       const float* __restrict__ m, const float* __restrict__ v,
                       float* __restrict__ out, size_t outStride) {
  int t = blockIdx.x * 256 + threadIdx.x;
  int p4 = t * 4;
  int n = p4 % N_;
  int c = (p4 / N_) % (2 * C_);
  int b = p4 / (2 * C_ * N_);
  size_t off = (size_t)c * N_ + n;
  float4 a = *(const float4*)(pA + (size_t)b * strideA + off);
  float4 d = *(const float4*)(pB + (size_t)b * strideB + off);
  float s  = g[c] * rsqrtf(v[c] + EPS_);
  float sh = b2[c] - m[c] * s;
  float4 r;
  r.x = fmaxf((a.x + d.x) * s + sh, 0.f);
  r.y = fmaxf((a.y + d.y) * s + sh, 0.f);
  r.z = fmaxf((a.z + d.z) * s + sh, 0.f);
  r.w = fmaxf((a.w + d.w) * s + sh, 0.f);
  *(float4*)(out + (size_t)b * outStride + off) = r;
}

// -------- final v2: 2 couts/block, fused comb(fbn2)+relu + cat add --------
__global__ __launch_bounds__(64) void k_final3(
    const float* __restrict__ pA, size_t strideA,
    const float* __restrict__ pB, size_t strideB,
    const float* __restrict__ g2, const float* __restrict__ b2,
    const float* __restrict__ m2, const float* __restrict__ v2,
    const float* __restrict__ cat,
    const float* __restrict__ w, const float* __restrict__ fb,
    float* __restrict__ out) {
  __shared__ float fsc[2 * C_], fsh[2 * C_];
  for (int j = threadIdx.x; j < 2 * C_; j += 64) {
    float s = g2[j] * rsqrtf(v2[j] + EPS_);
    fsc[j] = s;
    fsh[j] = b2[j] - m2[j] * s;
  }
  __syncthreads();
  int p = blockIdx.x * 128 + threadIdx.x * 2;
  int c0 = blockIdx.y * 2;
  int b = blockIdx.z;
  const float* frA = pA + (size_t)b * strideA;
  const float* frB = pB + (size_t)b * strideB;
  const float* wr0 = w + (size_t)c0 * 2 * C_;
  const float* wr1 = wr0 + 2 * C_;
  float a00 = fb[c0], a01 = a00;
  float a10 = fb[c0 + 1], a11 = a10;
#pragma unroll 4
  for (int j = 0; j < 2 * C_; ++j) {
    float2 fa = *(const float2*)(frA + (size_t)j * N_ + p);
    float2 fd = *(const float2*)(frB + (size_t)j * N_ + p);
    float s = fsc[j], sh = fsh[j];
    float f0 = fmaxf((fa.x + fd.x) * s + sh, 0.f);
    float f1 = fmaxf((fa.y + fd.y) * s + sh, 0.f);
    float wv0 = wr0[j], wv1 = wr1[j];
    a00 += wv0 * f0; a01 += wv0 * f1;
    a10 += wv1 * f0; a11 += wv1 * f1;
  }
  size_t o = ((size_t)b * 2 * C_ + c0) * N_ + p;
  float2 cv0 = *(const float2*)(cat + o);
  float2 cv1 = *(const float2*)(cat + o + N_);
  *(float2*)(out + o)      = make_float2(a00 + cv0.x, a01 + cv0.y);
  *(float2*)(out + o + N_) = make_float2(a10 + cv1.x, a11 + cv1.y);
}

extern "C" void kernel_launch(void* const* d_in, const int* in_sizes, int n_in,
                              void* d_out, int out_size, void* d_ws, size_t ws_size,
                              hipStream_t stream) {
  const float* x       = (const float*)d_in[0];
  const float* y       = (const float*)d_in[1];
  const float* pconv_w = (const float*)d_in[2];
  const float* pconv_b = (const float*)d_in[3];
  const float* bnd_g = (const float*)d_in[4];
  const float* bnd_b = (const float*)d_in[5];
  const float* bnd_m = (const float*)d_in[6];
  const float* bnd_v = (const float*)d_in[7];
  const float* lnx_g = (const float*)d_in[8];
  const float* lnx_b = (const float*)d_in[9];
  const float* lny_g = (const float*)d_in[10];
  const float* lny_b = (const float*)d_in[11];
  const float* lnz_g = (const float*)d_in[12];
  const float* lnz_b = (const float*)d_in[13];
  const float* k_w   = (const float*)d_in[14];
  const float* k_b   = (const float*)d_in[15];
  const float* qv_w  = (const float*)d_in[16];
  const float* qv_b  = (const float*)d_in[17];
  const float* proj_w = (const float*)d_in[18];
  const float* proj_b = (const float*)d_in[19];
  const float* c2w1  = (const float*)d_in[20];
  const float* c2b1  = (const float*)d_in[21];
  const float* c2bn1_g = (const float*)d_in[22];
  const float* c2bn1_b = (const float*)d_in[23];
  const float* c2bn1_m = (const float*)d_in[24];
  const float* c2bn1_v = (const float*)d_in[25];
  const float* c2w2  = (const float*)d_in[26];
  const float* c2b2  = (const float*)d_in[27];
  const float* c2bn2_g = (const float*)d_in[28];
  const float* c2bn2_b = (const float*)d_in[29];
  const float* c2bn2_m = (const float*)d_in[30];
  const float* c2bn2_v = (const float*)d_in[31];
  const float* bn2_g = (const float*)d_in[32];
  const float* bn2_b = (const float*)d_in[33];
  const float* bn2_m = (const float*)d_in[34];
  const float* bn2_v = (const float*)d_in[35];
  const float* f1w   = (const float*)d_in[36];
  const float* fbn1_g = (const float*)d_in[37];
  const float* fbn1_b = (const float*)d_in[38];
  const float* fbn1_m = (const float*)d_in[39];
  const float* fbn1_v = (const float*)d_in[40];
  const float* f2w   = (const float*)d_in[41];
  const float* fbn2_g = (const float*)d_in[42];
  const float* fbn2_b = (const float*)d_in[43];
  const float* fbn2_m = (const float*)d_in[44];
  const float* fbn2_v = (const float*)d_in[45];
  const float* f3w   = (const float*)d_in[46];
  const float* f3b   = (const float*)d_in[47];

  float* ws = (float*)d_ws;
  float* sl0 = ws + 0 * S_;
  float* sl1 = ws + 1 * S_;
  float* sl2 = ws + 2 * S_;
  float* sl3 = ws + 3 * S_;
  float* sl4 = ws + 4 * S_;
  float* sl5 = ws + 5 * S_;
  float* sl7 = ws + 7 * S_;

  // A. fused pconv + bn + ln (v2: 16 rows/block)
  k_pre<<<B_ * N_ / 16, 1024, 0, stream>>>(x, y, pconv_w, pconv_b,
                                    bnd_g, bnd_b, bnd_m, bnd_v,
                                    lnx_g, lnx_b, lny_g, lny_b, lnz_g, lnz_b,
                                    sl1, sl2, sl3);
  // B. qv/k projection v2 -> bf16 attention operands
  u16* qxb = (u16*)sl4;
  u16* qyb = qxb + (size_t)B_ * NH_ * N_ * 8;
  u16* kbf = (u16*)sl5;
  u16* vtb = (u16*)(ws + 6 * S_);
  {
    dim3 g(B_ * N_ / 64, 20);
    k_qvk<<<g, 64, 0, stream>>>(sl1, sl2, sl3, qv_w, qv_b, k_w, k_b,
                                qxb, qyb, kbf, vtb);
  }
  // C. attention v8 (MFMA) -> att_xo(1), att_yo(2)
  {
    dim3 g(N_ / 16, B_ * NH_);
    k_attn8<<<g, 128, 0, stream>>>(qxb, qyb, kbf, vtb, sl1, sl2);
  }
  // D. proj v2 (2 couts) -> xo4(3,4)
  {
    dim3 g(18, C_ / 2, 2 * B_);
    k_proj2<<<g, 64, 0, stream>>>(sl1, x, y, bnd_g, bnd_b, bnd_m, bnd_v,
                                  proj_w, proj_b, sl3);
  }
  // E. conv1: cin-split raw partials (4 px) + combine epilogue -> tmp(0 / 7)
  {
    dim3 g(9, C_ / 2, 8);
    k_convs<<<g, 64, 0, stream>>>(sl3, sl3 + 2 * CN_, c2w1, sl1, sl5);
    k_combp<<<576, 256, 0, stream>>>(sl1, sl5, c2b1,
        c2bn1_g, c2bn1_b, c2bn1_m, c2bn1_v, sl0, sl7);
  }
  // F. conv2: cin-split raw partials (4 px) + combine(+resid) -> o2(1,2)
  {
    dim3 g(9, C_ / 2, 8);
    k_convs<<<g, 64, 0, stream>>>(sl0, sl7, c2w2, sl1, sl5);
    k_comb2<<<576, 256, 0, stream>>>(sl1, sl5, c2b2,
        c2bn2_g, c2bn2_b, c2bn2_m, c2bn2_v, sl3);
  }
  // G. cat + bn2 -> cat(3,4), fin(0 / 7)
  k_catbn<<<576, 256, 0, stream>>>(sl1, bn2_g, bn2_b, bn2_m, bn2_v,
                                   sl3, sl0, 7 * S_);
  // H. f-branch convs, ci-split, 4 px/thread
  {
    dim3 g(9, C_, 2 * B_);
    k_fconvs<<<g, 64, 0, stream>>>(sl0, 7 * S_, f1w, sl1, S_, sl5, S_);
    k_comb<<<576, 256, 0, stream>>>(sl1, S_, sl5, S_,
                                    fbn1_g, fbn1_b, fbn1_m, fbn1_v, sl1, S_);
    k_fconvs<<<g, 64, 0, stream>>>(sl1, S_, f2w, sl5, S_, sl0, 7 * S_);
  }
  // I. final v2 (2 couts) -> fp32 out
  {
    dim3 g(18, C_, B_);
    k_final3<<<g, 64, 0, stream>>>(sl5, S_, sl0, 7 * S_,
                                   fbn2_g, fbn2_b, fbn2_m, fbn2_v,
                                   sl3, f3w, f3b, (float*)d_out);
  }
}